// Round 1
// baseline (671.846 us; speedup 1.0000x reference)
//
#include <hip/hip_runtime.h>
#include <hip/hip_bf16.h>
#include <hip/hip_fp16.h>
#include <cstdint>

typedef _Float16 f16;
typedef _Float16 f16x8 __attribute__((ext_vector_type(8)));
typedef _Float16 f16x4 __attribute__((ext_vector_type(4)));
typedef float f32x4 __attribute__((ext_vector_type(4)));

#define DEV_INLINE __device__ __forceinline__

// async 16B/lane global->LDS. LDS dest is wave-uniform base + lane*16.
DEV_INLINE void async_ld16(const void* g, void* l) {
  __builtin_amdgcn_global_load_lds((const __attribute__((address_space(1))) void*)g,
                                   (__attribute__((address_space(3))) void*)l, 16, 0, 0);
}

// ---------------- elementwise prep kernels ----------------

// x f32 [2048][4096] -> Acat f16 [2048][8192] = [hi(4096) | lo(4096)]
__global__ __launch_bounds__(256) void k_cast_x_split(const float* __restrict__ x,
                                                      f16* __restrict__ acat) {
  int idx = blockIdx.x * 256 + threadIdx.x;
  int i = idx * 4;
  if (i >= 2048 * 4096) return;
  float4 v = *(const float4*)&x[i];
  int row = i >> 12, col = i & 4095;
  f16 h0 = (f16)v.x, h1 = (f16)v.y, h2 = (f16)v.z, h3 = (f16)v.w;
  f16x4 hi = {h0, h1, h2, h3};
  f16x4 lo = {(f16)(v.x - (float)h0), (f16)(v.y - (float)h1),
              (f16)(v.z - (float)h2), (f16)(v.w - (float)h3)};
  size_t base = (size_t)row * 8192 + col;
  *(f16x4*)&acat[base] = hi;
  *(f16x4*)&acat[base + 4096] = lo;
}

// int32 weights (values in [-127,127], exact in f16) -> f16
__global__ __launch_bounds__(256) void k_cast_i32_f16(const int* __restrict__ w,
                                                      f16* __restrict__ out, int n) {
  int i = (blockIdx.x * 256 + threadIdx.x) * 4;
  if (i >= n) return;
  int4 v = *(const int4*)&w[i];
  f16x4 o = {(f16)(float)v.x, (f16)(float)v.y, (f16)(float)v.z, (f16)(float)v.w};
  *(f16x4*)&out[i] = o;
}

// concat bias [bq|bk|bv] and per-column scale [sq|sk|sv] over 6144 cols
__global__ __launch_bounds__(256) void k_prep_bs(const float* bq, const float* bk, const float* bv,
                                                 const float* sq, const float* sk, const float* sv,
                                                 float* bias_cat, float* scale_cat) {
  int i = blockIdx.x * 256 + threadIdx.x;
  if (i >= 6144) return;
  float b, s;
  if (i < 4096)      { b = bq[i];        s = sq[0]; }
  else if (i < 5120) { b = bk[i - 4096]; s = sk[0]; }
  else               { b = bv[i - 5120]; s = sv[0]; }
  bias_cat[i] = b;
  scale_cat[i] = s;
}

// ---------------- GEMM: C[M,N] = A[M,K] * W[N,ldw]^T (k wraps by kmask) ----------------
// MODE 0: out = hi/lo f16 pair, per-col scale+bias vectors (QKV projection, K=8192 split-x)
// MODE 1: out = f32, scalar scale, no bias (output projection)
template <int MODE>
__global__ __launch_bounds__(256) void k_gemm(const f16* __restrict__ A, const f16* __restrict__ W,
                                              f16* __restrict__ o_hi, f16* __restrict__ o_lo,
                                              float* __restrict__ o_f32,
                                              const float* __restrict__ scale_vec,
                                              const float* __restrict__ bias_vec,
                                              const float* __restrict__ scale_scalar,
                                              int M, int N, int K, int kmask, int ldw) {
  __shared__ __align__(16) f16 As[128 * 32];
  __shared__ __align__(16) f16 Bs[128 * 32];
  const int t = threadIdx.x, w = t >> 6, l = t & 63;
  const int lr = l & 15, lg = l >> 4;
  const int wm = w >> 1, wn = w & 1;
  const int n0 = blockIdx.x * 128, m0 = blockIdx.y * 128;
  f32x4 acc[4][4] = {};
  const int arow = t >> 2, ac8 = (t & 3) * 8;
  const f16* Ag = A + (size_t)(m0 + arow) * K + ac8;
  const f16* Wg = W + (size_t)(n0 + arow) * ldw + ac8;
  f16* AsW = &As[w * 512];  // wave-uniform LDS bases
  f16* BsW = &Bs[w * 512];

  for (int k0 = 0; k0 < K; k0 += 32) {
    const int wk0 = k0 & kmask;
    async_ld16(Ag + k0, AsW);
    async_ld16(Ag + k0 + (size_t)64 * K, AsW + 2048);
    async_ld16(Wg + wk0, BsW);
    async_ld16(Wg + wk0 + (size_t)64 * ldw, BsW + 2048);
    __syncthreads();  // drains vmcnt: staged tile visible
    f16x8 af[4], bf[4];
#pragma unroll
    for (int m = 0; m < 4; m++) af[m] = *(const f16x8*)&As[(wm * 64 + m * 16 + lr) * 32 + lg * 8];
#pragma unroll
    for (int n = 0; n < 4; n++) bf[n] = *(const f16x8*)&Bs[(wn * 64 + n * 16 + lr) * 32 + lg * 8];
#pragma unroll
    for (int m = 0; m < 4; m++)
#pragma unroll
      for (int n = 0; n < 4; n++)
        acc[m][n] = __builtin_amdgcn_mfma_f32_16x16x32_f16(af[m], bf[n], acc[m][n], 0, 0, 0);
    __syncthreads();  // protect LDS from next iteration's staging
  }

#pragma unroll
  for (int n = 0; n < 4; n++) {
    const int col = n0 + wn * 64 + n * 16 + lr;
    const float sc = (MODE == 0) ? scale_vec[col] : scale_scalar[0];
    const float bs = (MODE == 0) ? bias_vec[col] : 0.f;
#pragma unroll
    for (int m = 0; m < 4; m++)
#pragma unroll
      for (int r = 0; r < 4; r++) {
        const int row = m0 + wm * 64 + m * 16 + lg * 4 + r;
        const float v = acc[m][n][r] * sc + bs;
        if (MODE == 0) {
          f16 h = (f16)v;
          o_hi[(size_t)row * N + col] = h;
          o_lo[(size_t)row * N + col] = (f16)(v - (float)h);
        } else {
          o_f32[(size_t)row * N + col] = v;
        }
      }
  }
}

// ---------------- RoPE on split Q/K (cols 0..5119 of 6144), f32 math ----------------
__global__ __launch_bounds__(256) void k_rope(f16* __restrict__ XH, f16* __restrict__ XL,
                                              const float* __restrict__ cosT,
                                              const float* __restrict__ sinT,
                                              const int* __restrict__ sp) {
  int idx = blockIdx.x * 256 + threadIdx.x;  // 2048 tokens * 40 heads * 64 pairs
  if (idx >= 2048 * 40 * 64) return;
  int p = idx & 63;
  int hh = (idx >> 6) % 40;
  int tkn = idx / (40 * 64);
  int col = (hh < 32) ? hh * 128 + p : 4096 + (hh - 32) * 128 + p;
  size_t i1 = (size_t)tkn * 6144 + col, i2 = i1 + 64;
  float x1 = (float)XH[i1] + (float)XL[i1];
  float x2 = (float)XH[i2] + (float)XL[i2];
  int pos = (tkn & 1023) + sp[0];
  float c = cosT[pos * 128 + p], s = sinT[pos * 128 + p];  // c[p]==c[p+64], s[p]==s[p+64]
  float o1 = x1 * c - x2 * s;
  float o2 = x2 * c + x1 * s;
  f16 h1 = (f16)o1, h2 = (f16)o2;
  XH[i1] = h1; XL[i1] = (f16)(o1 - (float)h1);
  XH[i2] = h2; XL[i2] = (f16)(o2 - (float)h2);
}

// ---------------- flash attention, causal, GQA 4:1 ----------------
// grid (S/64, H, B), 256 threads = 4 waves, wave w owns q rows [q0+16w, q0+16w+16)
// QK^T: 3-term split (qh*kh + qh*kl + ql*kh) for ~f32-accurate scores.
__global__ __launch_bounds__(256) void k_attn(const f16* __restrict__ XH,
                                              const f16* __restrict__ XL,
                                              f16* __restrict__ out) {
  __shared__ __align__(16) f16 KsH[32 * 152];  // [key][d] pad 152 (2-way banks, 16B aligned)
  __shared__ __align__(16) f16 KsL[32 * 152];
  __shared__ __align__(16) f16 VT[128 * 40];   // [d][key] pad 40
  __shared__ __align__(16) f16 Pb[4 * 16 * 40];
  const int t = threadIdx.x, w = t >> 6, l = t & 63;
  const int lr = l & 15, lg = l >> 4;
  const int qb = blockIdx.x, h = blockIdx.y, b = blockIdx.z;
  const int q0 = qb * 64, kvh = h >> 2;
  const size_t rs_ = 6144;
  const f16* Qh = XH + ((size_t)(b * 1024 + q0)) * rs_ + h * 128;
  const f16* Ql_ = XL + ((size_t)(b * 1024 + q0)) * rs_ + h * 128;
  const f16* KhG = XH + ((size_t)(b * 1024)) * rs_ + 4096 + kvh * 128;
  const f16* KlG = XL + ((size_t)(b * 1024)) * rs_ + 4096 + kvh * 128;
  const f16* VG = XH + ((size_t)(b * 1024)) * rs_ + 5120 + kvh * 128;

  f16x8 qh[4], ql[4];
  {
    size_t qoff = (size_t)(w * 16 + lr) * rs_ + lg * 8;
#pragma unroll
    for (int c = 0; c < 4; c++) {
      qh[c] = *(const f16x8*)(Qh + qoff + c * 32);
      ql[c] = *(const f16x8*)(Ql_ + qoff + c * 32);
    }
  }
  f32x4 accd[8] = {};
  float m_r[4], l_r[4];
#pragma unroll
  for (int r = 0; r < 4; r++) { m_r[r] = -1e30f; l_r[r] = 0.f; }

  const int nkv = q0 + 64;  // causal: keys beyond q-tile never needed
  for (int kv0 = 0; kv0 < nkv; kv0 += 32) {
    __syncthreads();
    // stage K hi/lo [32][128] -> padded LDS (coalesced 16B reads)
#pragma unroll
    for (int i = 0; i < 2; i++) {
      int slot = i * 256 + t, row = slot >> 4, ch = slot & 15;
      size_t go = (size_t)(kv0 + row) * rs_ + ch * 8;
      *(f16x8*)&KsH[row * 152 + ch * 8] = *(const f16x8*)(KhG + go);
      *(f16x8*)&KsL[row * 152 + ch * 8] = *(const f16x8*)(KlG + go);
    }
    // stage V transposed: VT[d][key]
#pragma unroll
    for (int i = 0; i < 2; i++) {
      int slot = i * 256 + t, row = slot & 31, d8 = slot >> 5;
      f16x8 vv = *(const f16x8*)(VG + (size_t)(kv0 + row) * rs_ + d8 * 8);
#pragma unroll
      for (int j = 0; j < 8; j++) VT[(d8 * 8 + j) * 40 + row] = vv[j];
    }
    __syncthreads();

    // scores: S[q, k] over 16q x 32k, split 3-MFMA per (colblock, d-chunk)
    f32x4 sc[2] = {};
#pragma unroll
    for (int cb = 0; cb < 2; cb++)
#pragma unroll
      for (int c = 0; c < 4; c++) {
        const f16x8 kh = *(const f16x8*)&KsH[(cb * 16 + lr) * 152 + c * 32 + lg * 8];
        const f16x8 kl = *(const f16x8*)&KsL[(cb * 16 + lr) * 152 + c * 32 + lg * 8];
        sc[cb] = __builtin_amdgcn_mfma_f32_16x16x32_f16(qh[c], kh, sc[cb], 0, 0, 0);
        sc[cb] = __builtin_amdgcn_mfma_f32_16x16x32_f16(qh[c], kl, sc[cb], 0, 0, 0);
        sc[cb] = __builtin_amdgcn_mfma_f32_16x16x32_f16(ql[c], kh, sc[cb], 0, 0, 0);
      }

    const float scale = 0.088388347648318447f;  // 1/sqrt(128)
    float alpha[4], pv[2][4];
#pragma unroll
    for (int r = 0; r < 4; r++) {
      const int qg = q0 + w * 16 + lg * 4 + r;  // C-layout row
      float mx = -1e30f;
#pragma unroll
      for (int cb = 0; cb < 2; cb++) {
        const int kg = kv0 + cb * 16 + lr;  // C-layout col
        float s = sc[cb][r] * scale;
        s = (kg <= qg) ? s : -1e30f;
        pv[cb][r] = s;
        mx = fmaxf(mx, s);
      }
      mx = fmaxf(mx, __shfl_xor(mx, 1));
      mx = fmaxf(mx, __shfl_xor(mx, 2));
      mx = fmaxf(mx, __shfl_xor(mx, 4));
      mx = fmaxf(mx, __shfl_xor(mx, 8));
      const float mn = fmaxf(m_r[r], mx);
      alpha[r] = __expf(m_r[r] - mn);
      m_r[r] = mn;
      float rsum = 0.f;
#pragma unroll
      for (int cb = 0; cb < 2; cb++) {
        const int kg = kv0 + cb * 16 + lr;
        const float p = (kg <= qg) ? __expf(pv[cb][r] - mn) : 0.f;  // guard: masked stays 0
        pv[cb][r] = p;
        rsum += p;
      }
      rsum += __shfl_xor(rsum, 1);
      rsum += __shfl_xor(rsum, 2);
      rsum += __shfl_xor(rsum, 4);
      rsum += __shfl_xor(rsum, 8);
      l_r[r] = l_r[r] * alpha[r] + rsum;
    }

    // P (C-layout) -> per-wave LDS [16 q][40], then A-fragment read
    f16* Pw = &Pb[w * 16 * 40];
#pragma unroll
    for (int r = 0; r < 4; r++)
#pragma unroll
      for (int cb = 0; cb < 2; cb++)
        Pw[(lg * 4 + r) * 40 + cb * 16 + lr] = (f16)pv[cb][r];
    const f16x8 pf = *(const f16x8*)&Pw[lr * 40 + lg * 8];

    // PV: out[q, d] += P * V, 8 d-chunks of 16
#pragma unroll
    for (int dc = 0; dc < 8; dc++) {
      const f16x8 vf = *(const f16x8*)&VT[(dc * 16 + lr) * 40 + lg * 8];
#pragma unroll
      for (int r = 0; r < 4; r++) accd[dc][r] *= alpha[r];
      accd[dc] = __builtin_amdgcn_mfma_f32_16x16x32_f16(pf, vf, accd[dc], 0, 0, 0);
    }
  }

#pragma unroll
  for (int dc = 0; dc < 8; dc++)
#pragma unroll
    for (int r = 0; r < 4; r++) {
      const int row = b * 1024 + q0 + w * 16 + lg * 4 + r;
      out[(size_t)row * 4096 + h * 128 + dc * 16 + lr] = (f16)(accd[dc][r] / l_r[r]);
    }
}

// ---------------- launch ----------------
extern "C" void kernel_launch(void* const* d_in, const int* in_sizes, int n_in,
                              void* d_out, int out_size, void* d_ws, size_t ws_size,
                              hipStream_t stream) {
  const float* x = (const float*)d_in[0];
  // d_in[1] = mask (causal triu, known analytically; unused)
  const float* cosT = (const float*)d_in[2];
  const float* sinT = (const float*)d_in[3];
  const int* wq = (const int*)d_in[4];
  const float* bq = (const float*)d_in[5];
  const float* sq = (const float*)d_in[6];
  const int* wk = (const int*)d_in[7];
  const float* bk = (const float*)d_in[8];
  const float* sk = (const float*)d_in[9];
  const int* wv = (const int*)d_in[10];
  const float* bv = (const float*)d_in[11];
  const float* sv = (const float*)d_in[12];
  const int* wo = (const int*)d_in[13];
  const float* so = (const float*)d_in[14];
  const int* sp = (const int*)d_in[15];

  char* ws = (char*)d_ws;
  f16* Acat = (f16*)ws;                        // 33,554,432 B  (x hi|lo; later reused for Wo)
  f16* Wcat = (f16*)(ws + 33554432);           // 50,331,648 B  (wq|wk|wv f16)
  f16* XH = (f16*)(ws + 83886080);             // 25,165,824 B  (qkv hi, [2048][6144])
  f16* XL = (f16*)(ws + 109051904);            // 25,165,824 B  (qkv lo)
  f16* AO = (f16*)(ws + 134217728);            // 16,777,216 B  (attn out, [2048][4096])
  float* biasv = (float*)(ws + 150994944);     // 24,576 B
  float* scalev = (float*)(ws + 151019520);    // 24,576 B
  // total: ~151.1 MB of d_ws

  k_cast_x_split<<<8192, 256, 0, stream>>>(x, Acat);
  k_cast_i32_f16<<<16384, 256, 0, stream>>>(wq, Wcat, 16777216);
  k_cast_i32_f16<<<4096, 256, 0, stream>>>(wk, Wcat + (size_t)4096 * 4096, 4194304);
  k_cast_i32_f16<<<4096, 256, 0, stream>>>(wv, Wcat + (size_t)5120 * 4096, 4194304);
  k_prep_bs<<<24, 256, 0, stream>>>(bq, bk, bv, sq, sk, sv, biasv, scalev);

  // fused QKV projection, split-x (K = 2*4096, W k-index wraps)
  k_gemm<0><<<dim3(48, 16), 256, 0, stream>>>(Acat, Wcat, XH, XL, nullptr, scalev, biasv,
                                              nullptr, 2048, 6144, 8192, 4095, 4096);
  k_rope<<<20480, 256, 0, stream>>>(XH, XL, cosT, sinT, sp);

  f16* Wo_ = Acat;  // Acat dead after QKV GEMM; exact-size reuse
  k_cast_i32_f16<<<16384, 256, 0, stream>>>(wo, Wo_, 16777216);

  k_attn<<<dim3(16, 32, 2), 256, 0, stream>>>(XH, XL, AO);

  // output projection -> f32
  k_gemm<1><<<dim3(32, 16), 256, 0, stream>>>(AO, Wo_, nullptr, nullptr, (float*)d_out, nullptr,
                                              nullptr, so, 2048, 4096, 4096, 0x7fffffff, 4096);
}

// Round 2
// 569.035 us; speedup vs baseline: 1.1807x; 1.1807x over previous
//
#include <hip/hip_runtime.h>
#include <hip/hip_bf16.h>
#include <hip/hip_fp16.h>
#include <cstdint>

typedef _Float16 f16;
typedef _Float16 f16x8 __attribute__((ext_vector_type(8)));
typedef _Float16 f16x4 __attribute__((ext_vector_type(4)));
typedef float f32x4 __attribute__((ext_vector_type(4)));

#define DEV_INLINE __device__ __forceinline__

// async 16B/lane global->LDS. LDS dest is wave-uniform base + lane*16.
DEV_INLINE void async_ld16(const void* g, void* l) {
  __builtin_amdgcn_global_load_lds((const __attribute__((address_space(1))) void*)g,
                                   (__attribute__((address_space(3))) void*)l, 16, 0, 0);
}

DEV_INLINE void wait_vm_rt(int n) {
  switch (n) {
    case 0: asm volatile("s_waitcnt vmcnt(0)" ::: "memory"); break;
    case 3: asm volatile("s_waitcnt vmcnt(3)" ::: "memory"); break;
    case 4: asm volatile("s_waitcnt vmcnt(4)" ::: "memory"); break;
    case 6: asm volatile("s_waitcnt vmcnt(6)" ::: "memory"); break;
    case 8: asm volatile("s_waitcnt vmcnt(8)" ::: "memory"); break;
    default: asm volatile("s_waitcnt vmcnt(9)" ::: "memory"); break;
  }
}

// ---------------- elementwise prep kernels ----------------

// x f32 [2048][4096] -> Acat f16 [2048][8192] = [hi(4096) | lo(4096)]
__global__ __launch_bounds__(256) void k_cast_x_split(const float* __restrict__ x,
                                                      f16* __restrict__ acat) {
  int idx = blockIdx.x * 256 + threadIdx.x;
  int i = idx * 4;
  if (i >= 2048 * 4096) return;
  float4 v = *(const float4*)&x[i];
  int row = i >> 12, col = i & 4095;
  f16 h0 = (f16)v.x, h1 = (f16)v.y, h2 = (f16)v.z, h3 = (f16)v.w;
  f16x4 hi = {h0, h1, h2, h3};
  f16x4 lo = {(f16)(v.x - (float)h0), (f16)(v.y - (float)h1),
              (f16)(v.z - (float)h2), (f16)(v.w - (float)h3)};
  size_t base = (size_t)row * 8192 + col;
  *(f16x4*)&acat[base] = hi;
  *(f16x4*)&acat[base + 4096] = lo;
}

// int32 weights (values in [-127,127], exact in f16) -> f16
__global__ __launch_bounds__(256) void k_cast_i32_f16(const int* __restrict__ w,
                                                      f16* __restrict__ out, int n) {
  int i = (blockIdx.x * 256 + threadIdx.x) * 4;
  if (i >= n) return;
  int4 v = *(const int4*)&w[i];
  f16x4 o = {(f16)(float)v.x, (f16)(float)v.y, (f16)(float)v.z, (f16)(float)v.w};
  *(f16x4*)&out[i] = o;
}

// concat bias [bq|bk|bv] and per-column scale [sq|sk|sv] over 6144 cols
__global__ __launch_bounds__(256) void k_prep_bs(const float* bq, const float* bk, const float* bv,
                                                 const float* sq, const float* sk, const float* sv,
                                                 float* bias_cat, float* scale_cat) {
  int i = blockIdx.x * 256 + threadIdx.x;
  if (i >= 6144) return;
  float b, s;
  if (i < 4096)      { b = bq[i];        s = sq[0]; }
  else if (i < 5120) { b = bk[i - 4096]; s = sk[0]; }
  else               { b = bv[i - 5120]; s = sv[0]; }
  bias_cat[i] = b;
  scale_cat[i] = s;
}

// ---------------- GEMM v2: counted-vmcnt 4-slot ring, BK=32, swizzled LDS ----------------
// C[M,N] = A[M,K] * W[N,ldw]^T, k wraps by kmask on the W side.
// 512 threads = 8 waves (2M x 4N). Per K-tile(32): per-wave 12 ds_read_b128, 32 MFMA.
// Ring: stage tile t+3 each iter, gate vmcnt(3*LPT) -> 3 tiles always in flight (never 0).
// Chunk swizzle c ^= (row>>2)&3 applied to GLOBAL source (linear global_load_lds dest)
// and to ds_read address -> conflict-free fragment reads.
template <int BM, int BN, int MODE>
__global__ __launch_bounds__(512) void k_gemm2(
    const f16* __restrict__ A, const f16* __restrict__ W,
    f16* __restrict__ o_hi, f16* __restrict__ o_lo, float* __restrict__ o_f32,
    const float* __restrict__ scale_vec, const float* __restrict__ bias_vec,
    const float* __restrict__ scale_scalar,
    int N, int K, int kmask, int ldw, int nym) {
  constexpr int WM = 2, WN = 4;
  constexpr int MR = BM / WM / 16;     // m-frags per wave
  constexpr int NR = BN / WN / 16;     // n-frags per wave
  constexpr int CA = BM * 4;           // 16B chunks per A tile (64B per row of 32 f16)
  constexpr int CB = BN * 4;
  constexpr int LA = CA / 512, LB = CB / 512, LPT = LA + LB;
  constexpr int SLOT = (CA + CB) * 16; // bytes per ring slot
  extern __shared__ __align__(16) char lds[];

  const int t = threadIdx.x, w = t >> 6, ln = t & 63;
  const int lr = ln & 15, lg = ln >> 4;
  const int wn = w & 3, wm = w >> 2;

  // T1: bijective XCD swizzle (m204 formula)
  const int nwg = gridDim.x;
  const int q = nwg >> 3, r8 = nwg & 7;
  const int xcd = blockIdx.x & 7, idx = blockIdx.x >> 3;
  const int sid = (xcd < r8 ? xcd * (q + 1) : r8 * (q + 1) + (xcd - r8) * q) + idx;
  const int m0 = (sid % nym) * BM;
  const int n0 = (sid / nym) * BN;

  // per-thread staging sources (global addr carries the chunk swizzle)
  const f16* asrc[LA];
  const f16* wsrc[LB];
#pragma unroll
  for (int i = 0; i < LA; i++) {
    int ci = i * 512 + t, rr = ci >> 2, c = ci & 3;
    int cs = c ^ ((rr >> 2) & 3);
    asrc[i] = A + (size_t)(m0 + rr) * K + cs * 8;
  }
#pragma unroll
  for (int i = 0; i < LB; i++) {
    int ci = i * 512 + t, rr = ci >> 2, c = ci & 3;
    int cs = c ^ ((rr >> 2) & 3);
    wsrc[i] = W + (size_t)(n0 + rr) * ldw + cs * 8;
  }

  f32x4 acc[MR][NR] = {};

  auto stage = [&](int tt) {
    const int slot = tt & 3;
    char* sA = lds + slot * SLOT;
    char* sB = sA + CA * 16;
    const int k0 = tt * 32;
    const int wk0 = k0 & kmask;
#pragma unroll
    for (int i = 0; i < LA; i++)
      async_ld16(asrc[i] + k0, sA + (i * 512 + w * 64) * 16);
#pragma unroll
    for (int i = 0; i < LB; i++)
      async_ld16(wsrc[i] + wk0, sB + (i * 512 + w * 64) * 16);
  };

  auto compute = [&](int tt) {
    const int slot = tt & 3;
    const f16* rA = (const f16*)(lds + slot * SLOT);
    const f16* rB = (const f16*)(lds + slot * SLOT + CA * 16);
    f16x8 af[MR], bf[NR];
#pragma unroll
    for (int m = 0; m < MR; m++) {
      const int row = wm * (BM / WM) + m * 16 + lr;
      af[m] = *(const f16x8*)(rA + row * 32 + (lg ^ ((row >> 2) & 3)) * 8);
    }
#pragma unroll
    for (int n = 0; n < NR; n++) {
      const int row = wn * (NR * 16) + n * 16 + lr;
      bf[n] = *(const f16x8*)(rB + row * 32 + (lg ^ ((row >> 2) & 3)) * 8);
    }
    __builtin_amdgcn_s_setprio(1);
#pragma unroll
    for (int m = 0; m < MR; m++)
#pragma unroll
      for (int n = 0; n < NR; n++)
        acc[m][n] = __builtin_amdgcn_mfma_f32_16x16x32_f16(af[m], bf[n], acc[m][n], 0, 0, 0);
    __builtin_amdgcn_s_setprio(0);
  };

  const int NT = K >> 5;
  stage(0); stage(1); stage(2);
  for (int tt = 0; tt < NT - 3; ++tt) {
    stage(tt + 3);  // slot (tt+3)&3 freed at end of iter tt-1
    if constexpr (LPT == 4) asm volatile("s_waitcnt vmcnt(12)" ::: "memory");
    else                    asm volatile("s_waitcnt vmcnt(9)" ::: "memory");
    __builtin_amdgcn_s_barrier();       // all waves' tile-tt chunks landed
    __builtin_amdgcn_sched_barrier(0);  // no ds_read hoist above barrier
    compute(tt);
    asm volatile("s_waitcnt lgkmcnt(0)" ::: "memory");
    __builtin_amdgcn_sched_barrier(0);
    __builtin_amdgcn_s_barrier();       // protect slot reuse by next stage
  }
  for (int tt = NT - 3; tt < NT; ++tt) {  // drain tail: 8/4/0 (or 6/3/0)
    wait_vm_rt(LPT * (NT - 1 - tt));
    __builtin_amdgcn_s_barrier();
    __builtin_amdgcn_sched_barrier(0);
    compute(tt);
    asm volatile("s_waitcnt lgkmcnt(0)" ::: "memory");
    __builtin_amdgcn_sched_barrier(0);
    __builtin_amdgcn_s_barrier();
  }

#pragma unroll
  for (int n = 0; n < NR; n++) {
    const int col = n0 + wn * (NR * 16) + n * 16 + lr;
    const float sc = (MODE == 0) ? scale_vec[col] : scale_scalar[0];
    const float bs = (MODE == 0) ? bias_vec[col] : 0.f;
#pragma unroll
    for (int m = 0; m < MR; m++)
#pragma unroll
      for (int rr2 = 0; rr2 < 4; rr2++) {
        const int row = m0 + wm * (BM / WM) + m * 16 + lg * 4 + rr2;
        const float v = acc[m][n][rr2] * sc + bs;
        if constexpr (MODE == 0) {
          f16 h = (f16)v;
          o_hi[(size_t)row * N + col] = h;
          o_lo[(size_t)row * N + col] = (f16)(v - (float)h);
        } else {
          o_f32[(size_t)row * N + col] = v;
        }
      }
  }
}

// ---------------- RoPE on split Q/K (cols 0..5119 of 6144), f32 math ----------------
__global__ __launch_bounds__(256) void k_rope(f16* __restrict__ XH, f16* __restrict__ XL,
                                              const float* __restrict__ cosT,
                                              const float* __restrict__ sinT,
                                              const int* __restrict__ sp) {
  int idx = blockIdx.x * 256 + threadIdx.x;  // 2048 tokens * 40 heads * 64 pairs
  if (idx >= 2048 * 40 * 64) return;
  int p = idx & 63;
  int hh = (idx >> 6) % 40;
  int tkn = idx / (40 * 64);
  int col = (hh < 32) ? hh * 128 + p : 4096 + (hh - 32) * 128 + p;
  size_t i1 = (size_t)tkn * 6144 + col, i2 = i1 + 64;
  float x1 = (float)XH[i1] + (float)XL[i1];
  float x2 = (float)XH[i2] + (float)XL[i2];
  int pos = (tkn & 1023) + sp[0];
  float c = cosT[pos * 128 + p], s = sinT[pos * 128 + p];
  float o1 = x1 * c - x2 * s;
  float o2 = x2 * c + x1 * s;
  f16 h1 = (f16)o1, h2 = (f16)o2;
  XH[i1] = h1; XL[i1] = (f16)(o1 - (float)h1);
  XH[i2] = h2; XL[i2] = (f16)(o2 - (float)h2);
}

// ---------------- flash attention, causal, GQA 4:1 ----------------
__global__ __launch_bounds__(256) void k_attn(const f16* __restrict__ XH,
                                              const f16* __restrict__ XL,
                                              f16* __restrict__ out) {
  __shared__ __align__(16) f16 KsH[32 * 152];
  __shared__ __align__(16) f16 KsL[32 * 152];
  __shared__ __align__(16) f16 VT[128 * 40];
  __shared__ __align__(16) f16 Pb[4 * 16 * 40];
  const int t = threadIdx.x, w = t >> 6, l = t & 63;
  const int lr = l & 15, lg = l >> 4;
  const int qb = blockIdx.x, h = blockIdx.y, b = blockIdx.z;
  const int q0 = qb * 64, kvh = h >> 2;
  const size_t rs_ = 6144;
  const f16* Qh = XH + ((size_t)(b * 1024 + q0)) * rs_ + h * 128;
  const f16* Ql_ = XL + ((size_t)(b * 1024 + q0)) * rs_ + h * 128;
  const f16* KhG = XH + ((size_t)(b * 1024)) * rs_ + 4096 + kvh * 128;
  const f16* KlG = XL + ((size_t)(b * 1024)) * rs_ + 4096 + kvh * 128;
  const f16* VG = XH + ((size_t)(b * 1024)) * rs_ + 5120 + kvh * 128;

  f16x8 qh[4], ql[4];
  {
    size_t qoff = (size_t)(w * 16 + lr) * rs_ + lg * 8;
#pragma unroll
    for (int c = 0; c < 4; c++) {
      qh[c] = *(const f16x8*)(Qh + qoff + c * 32);
      ql[c] = *(const f16x8*)(Ql_ + qoff + c * 32);
    }
  }
  f32x4 accd[8] = {};
  float m_r[4], l_r[4];
#pragma unroll
  for (int r = 0; r < 4; r++) { m_r[r] = -1e30f; l_r[r] = 0.f; }

  const int nkv = q0 + 64;
  for (int kv0 = 0; kv0 < nkv; kv0 += 32) {
    __syncthreads();
#pragma unroll
    for (int i = 0; i < 2; i++) {
      int slot = i * 256 + t, row = slot >> 4, ch = slot & 15;
      size_t go = (size_t)(kv0 + row) * rs_ + ch * 8;
      *(f16x8*)&KsH[row * 152 + ch * 8] = *(const f16x8*)(KhG + go);
      *(f16x8*)&KsL[row * 152 + ch * 8] = *(const f16x8*)(KlG + go);
    }
#pragma unroll
    for (int i = 0; i < 2; i++) {
      int slot = i * 256 + t, row = slot & 31, d8 = slot >> 5;
      f16x8 vv = *(const f16x8*)(VG + (size_t)(kv0 + row) * rs_ + d8 * 8);
#pragma unroll
      for (int j = 0; j < 8; j++) VT[(d8 * 8 + j) * 40 + row] = vv[j];
    }
    __syncthreads();

    f32x4 sc[2] = {};
#pragma unroll
    for (int cb = 0; cb < 2; cb++)
#pragma unroll
      for (int c = 0; c < 4; c++) {
        const f16x8 kh = *(const f16x8*)&KsH[(cb * 16 + lr) * 152 + c * 32 + lg * 8];
        const f16x8 kl = *(const f16x8*)&KsL[(cb * 16 + lr) * 152 + c * 32 + lg * 8];
        sc[cb] = __builtin_amdgcn_mfma_f32_16x16x32_f16(qh[c], kh, sc[cb], 0, 0, 0);
        sc[cb] = __builtin_amdgcn_mfma_f32_16x16x32_f16(qh[c], kl, sc[cb], 0, 0, 0);
        sc[cb] = __builtin_amdgcn_mfma_f32_16x16x32_f16(ql[c], kh, sc[cb], 0, 0, 0);
      }

    const float scale = 0.088388347648318447f;
    float alpha[4], pv[2][4];
#pragma unroll
    for (int r = 0; r < 4; r++) {
      const int qg = q0 + w * 16 + lg * 4 + r;
      float mx = -1e30f;
#pragma unroll
      for (int cb = 0; cb < 2; cb++) {
        const int kg = kv0 + cb * 16 + lr;
        float s = sc[cb][r] * scale;
        s = (kg <= qg) ? s : -1e30f;
        pv[cb][r] = s;
        mx = fmaxf(mx, s);
      }
      mx = fmaxf(mx, __shfl_xor(mx, 1));
      mx = fmaxf(mx, __shfl_xor(mx, 2));
      mx = fmaxf(mx, __shfl_xor(mx, 4));
      mx = fmaxf(mx, __shfl_xor(mx, 8));
      const float mn = fmaxf(m_r[r], mx);
      alpha[r] = __expf(m_r[r] - mn);
      m_r[r] = mn;
      float rsum = 0.f;
#pragma unroll
      for (int cb = 0; cb < 2; cb++) {
        const int kg = kv0 + cb * 16 + lr;
        const float p = (kg <= qg) ? __expf(pv[cb][r] - mn) : 0.f;
        pv[cb][r] = p;
        rsum += p;
      }
      rsum += __shfl_xor(rsum, 1);
      rsum += __shfl_xor(rsum, 2);
      rsum += __shfl_xor(rsum, 4);
      rsum += __shfl_xor(rsum, 8);
      l_r[r] = l_r[r] * alpha[r] + rsum;
    }

    f16* Pw = &Pb[w * 16 * 40];
#pragma unroll
    for (int r = 0; r < 4; r++)
#pragma unroll
      for (int cb = 0; cb < 2; cb++)
        Pw[(lg * 4 + r) * 40 + cb * 16 + lr] = (f16)pv[cb][r];
    const f16x8 pf = *(const f16x8*)&Pw[lr * 40 + lg * 8];

#pragma unroll
    for (int dc = 0; dc < 8; dc++) {
      const f16x8 vf = *(const f16x8*)&VT[(dc * 16 + lr) * 40 + lg * 8];
#pragma unroll
      for (int r = 0; r < 4; r++) accd[dc][r] *= alpha[r];
      accd[dc] = __builtin_amdgcn_mfma_f32_16x16x32_f16(pf, vf, accd[dc], 0, 0, 0);
    }
  }

#pragma unroll
  for (int dc = 0; dc < 8; dc++)
#pragma unroll
    for (int r = 0; r < 4; r++) {
      const int row = b * 1024 + q0 + w * 16 + lg * 4 + r;
      out[(size_t)row * 4096 + h * 128 + dc * 16 + lr] = (f16)(accd[dc][r] / l_r[r]);
    }
}

// ---------------- launch ----------------
extern "C" void kernel_launch(void* const* d_in, const int* in_sizes, int n_in,
                              void* d_out, int out_size, void* d_ws, size_t ws_size,
                              hipStream_t stream) {
  const float* x = (const float*)d_in[0];
  const float* cosT = (const float*)d_in[2];
  const float* sinT = (const float*)d_in[3];
  const int* wq = (const int*)d_in[4];
  const float* bq = (const float*)d_in[5];
  const float* sq = (const float*)d_in[6];
  const int* wk = (const int*)d_in[7];
  const float* bk = (const float*)d_in[8];
  const float* sk = (const float*)d_in[9];
  const int* wv = (const int*)d_in[10];
  const float* bv = (const float*)d_in[11];
  const float* sv = (const float*)d_in[12];
  const int* wo = (const int*)d_in[13];
  const float* so = (const float*)d_in[14];
  const int* sp = (const int*)d_in[15];

  char* ws = (char*)d_ws;
  f16* Acat = (f16*)ws;                        // x hi|lo [2048][8192]; later reused for Wo
  f16* Wcat = (f16*)(ws + 33554432);           // wq|wk|wv f16 [6144][4096]
  f16* XH = (f16*)(ws + 83886080);             // qkv hi [2048][6144]
  f16* XL = (f16*)(ws + 109051904);            // qkv lo
  f16* AO = (f16*)(ws + 134217728);            // attn out [2048][4096]
  float* biasv = (float*)(ws + 150994944);
  float* scalev = (float*)(ws + 151019520);

  hipFuncSetAttribute(reinterpret_cast<const void*>(&k_gemm2<256, 256, 0>),
                      hipFuncAttributeMaxDynamicSharedMemorySize, 131072);
  hipFuncSetAttribute(reinterpret_cast<const void*>(&k_gemm2<128, 256, 1>),
                      hipFuncAttributeMaxDynamicSharedMemorySize, 98304);

  k_cast_x_split<<<8192, 256, 0, stream>>>(x, Acat);
  k_cast_i32_f16<<<16384, 256, 0, stream>>>(wq, Wcat, 16777216);
  k_cast_i32_f16<<<4096, 256, 0, stream>>>(wk, Wcat + (size_t)4096 * 4096, 4194304);
  k_cast_i32_f16<<<4096, 256, 0, stream>>>(wv, Wcat + (size_t)5120 * 4096, 4194304);
  k_prep_bs<<<24, 256, 0, stream>>>(bq, bk, bv, sq, sk, sv, biasv, scalev);

  // fused QKV projection (split-x, K=8192, W k-index wraps at 4096)
  // grid: 8 M-tiles x 24 N-tiles = 192 blocks (M fastest -> W-panel reuse per XCD)
  k_gemm2<256, 256, 0><<<192, 512, 131072, stream>>>(
      Acat, Wcat, XH, XL, nullptr, scalev, biasv, nullptr, 6144, 8192, 4095, 4096, 8);

  k_rope<<<20480, 256, 0, stream>>>(XH, XL, cosT, sinT, sp);

  f16* Wo_ = Acat;  // Acat dead after QKV GEMM
  k_cast_i32_f16<<<16384, 256, 0, stream>>>(wo, Wo_, 16777216);

  k_attn<<<dim3(16, 32, 2), 256, 0, stream>>>(XH, XL, AO);

  // output projection -> f32; 16 M-tiles x 16 N-tiles = 256 blocks
  k_gemm2<128, 256, 1><<<256, 512, 98304, stream>>>(
      AO, Wo_, nullptr, nullptr, (float*)d_out, nullptr, nullptr, so, 4096, 4096,
      0x7fffffff, 4096, 16);
}

// Round 3
// 551.089 us; speedup vs baseline: 1.2191x; 1.0326x over previous
//
#include <hip/hip_runtime.h>
#include <hip/hip_bf16.h>
#include <hip/hip_fp16.h>
#include <cstdint>

typedef _Float16 f16;
typedef _Float16 f16x8 __attribute__((ext_vector_type(8)));
typedef _Float16 f16x4 __attribute__((ext_vector_type(4)));
typedef float f32x4 __attribute__((ext_vector_type(4)));

#define DEV_INLINE __device__ __forceinline__

// async 16B/lane global->LDS. LDS dest is wave-uniform base + lane*16.
DEV_INLINE void async_ld16(const void* g, void* l) {
  __builtin_amdgcn_global_load_lds((const __attribute__((address_space(1))) void*)g,
                                   (__attribute__((address_space(3))) void*)l, 16, 0, 0);
}

// ---------------- elementwise prep kernels ----------------

// x f32 [2048][4096] -> Acat f16 [2048][8192] = [hi(4096) | lo(4096)]
__global__ __launch_bounds__(256) void k_cast_x_split(const float* __restrict__ x,
                                                      f16* __restrict__ acat) {
  int idx = blockIdx.x * 256 + threadIdx.x;
  int i = idx * 4;
  if (i >= 2048 * 4096) return;
  float4 v = *(const float4*)&x[i];
  int row = i >> 12, col = i & 4095;
  f16 h0 = (f16)v.x, h1 = (f16)v.y, h2 = (f16)v.z, h3 = (f16)v.w;
  f16x4 hi = {h0, h1, h2, h3};
  f16x4 lo = {(f16)(v.x - (float)h0), (f16)(v.y - (float)h1),
              (f16)(v.z - (float)h2), (f16)(v.w - (float)h3)};
  size_t base = (size_t)row * 8192 + col;
  *(f16x4*)&acat[base] = hi;
  *(f16x4*)&acat[base + 4096] = lo;
}

// int32 weights (values in [-127,127], exact in f16) -> f16
__global__ __launch_bounds__(256) void k_cast_i32_f16(const int* __restrict__ w,
                                                      f16* __restrict__ out, int n) {
  int i = (blockIdx.x * 256 + threadIdx.x) * 4;
  if (i >= n) return;
  int4 v = *(const int4*)&w[i];
  f16x4 o = {(f16)(float)v.x, (f16)(float)v.y, (f16)(float)v.z, (f16)(float)v.w};
  *(f16x4*)&out[i] = o;
}

// concat bias [bq|bk|bv] and per-column scale [sq|sk|sv] over 6144 cols
__global__ __launch_bounds__(256) void k_prep_bs(const float* bq, const float* bk, const float* bv,
                                                 const float* sq, const float* sk, const float* sv,
                                                 float* bias_cat, float* scale_cat) {
  int i = blockIdx.x * 256 + threadIdx.x;
  if (i >= 6144) return;
  float b, s;
  if (i < 4096)      { b = bq[i];        s = sq[0]; }
  else if (i < 5120) { b = bk[i - 4096]; s = sk[0]; }
  else               { b = bv[i - 5120]; s = sv[0]; }
  bias_cat[i] = b;
  scale_cat[i] = s;
}

// ---------------- GEMM v3: 4-phase/K-tile interleave (m201-style), BK=64 ----------------
// C[M,N] = A[M,K] * W[N,ldw]^T, k wraps by kmask on the W side.
// 512 threads = 8 waves (2M x 4N). Double-buffered LDS, each buffer:
//   A as [kc][BM][32 f16], B as [kc][BN][32 f16] (kc-blocks contiguous so
//   global_load_lds dest stays linear; chunk swizzle c^=(row>>1)&3 via global src).
// Per K-tile: 4 phases, each {ds_read quadrant frags | stage kc-half of t+2 ->
//   barrier -> lgkmcnt(0) -> setprio+16 MFMA -> barrier}. vmcnt(LPT) once per
//   tile (never 0 until drain): one tile's loads in flight, tile t+1 landed.
// Race-freedom: B blocks of tile t last read at p1 -> staged (t+2) at p2/p3;
//   A blocks last read at p2 -> staged at p3; all stages after closing barriers.
template <int BM, int BN, int MODE>
__global__ __launch_bounds__(512) void k_gemm3(
    const f16* __restrict__ A, const f16* __restrict__ W,
    f16* __restrict__ o_hi, f16* __restrict__ o_lo, float* __restrict__ o_f32,
    const float* __restrict__ scale_vec, const float* __restrict__ bias_vec,
    const float* __restrict__ scale_scalar,
    int N, int K, int kmask, int ldw, int nym) {
  constexpr int WM = 2, WN = 4;
  constexpr int MR = BM / WM / 16, NR = BN / WN / 16;
  constexpr int MH = MR / 2, NH = NR / 2;
  constexpr int AKC = BM * 64;          // bytes per A kc-block (BM rows x 32 f16)
  constexpr int BKC = BN * 64;
  constexpr int ABYT = 2 * AKC, BBYT = 2 * BKC;
  constexpr int SLOT = ABYT + BBYT;     // one K-tile buffer
  constexpr int LAH = AKC / 8192;       // loads/thread per A kc-block
  constexpr int LBH = BKC / 8192;
  constexpr int LPT = 2 * (LAH + LBH);  // loads/thread per K-tile
  extern __shared__ __align__(16) char lds[];

  const int t = threadIdx.x, w = t >> 6, ln = t & 63;
  const int lr = ln & 15, lg = ln >> 4;
  const int wn = w & 3, wm = w >> 2;

  // T1: bijective XCD swizzle (m204)
  const int nwg = gridDim.x;
  const int q8 = nwg >> 3, r8 = nwg & 7;
  const int xcd = blockIdx.x & 7, bidx = blockIdx.x >> 3;
  const int sid = (xcd < r8 ? xcd * (q8 + 1) : r8 * (q8 + 1) + (xcd - r8) * q8) + bidx;
  const int m0 = (sid % nym) * BM;
  const int n0 = (sid / nym) * BN;

  // per-thread staging sources (global addr carries the chunk swizzle)
  const f16* aSrc[LAH];
  const f16* bSrc[LBH];
#pragma unroll
  for (int l = 0; l < LAH; l++) {
    int ci = l * 512 + t, row = ci >> 2, c = ci & 3;
    int cg = c ^ ((row >> 1) & 3);
    aSrc[l] = A + (size_t)(m0 + row) * K + cg * 8;
  }
#pragma unroll
  for (int l = 0; l < LBH; l++) {
    int ci = l * 512 + t, row = ci >> 2, c = ci & 3;
    int cg = c ^ ((row >> 1) & 3);
    bSrc[l] = W + (size_t)(n0 + row) * ldw + cg * 8;
  }

  f32x4 acc[MR][NR] = {};
  f16x8 af[MH][2], bfl[NH][2], bfh[NH][2];

  auto stageA = [&](int tt, int kc) {
    char* dst = lds + (tt & 1) * SLOT + kc * AKC;
    const int ko = tt * 64 + kc * 32;
#pragma unroll
    for (int l = 0; l < LAH; l++)
      async_ld16(aSrc[l] + ko, dst + (l * 512 + w * 64) * 16);
  };
  auto stageB = [&](int tt, int kc) {
    char* dst = lds + (tt & 1) * SLOT + ABYT + kc * BKC;
    const int ko = ((tt * 64) & kmask) + kc * 32;
#pragma unroll
    for (int l = 0; l < LBH; l++)
      async_ld16(bSrc[l] + ko, dst + (l * 512 + w * 64) * 16);
  };
  auto readA = [&](int tt, int mq) {
    const char* base = lds + (tt & 1) * SLOT;
#pragma unroll
    for (int mf = 0; mf < MH; mf++) {
      const int row = wm * (BM / WM) + (mq * MH + mf) * 16 + lr;
      const int swz = lg ^ ((row >> 1) & 3);
#pragma unroll
      for (int kc = 0; kc < 2; kc++)
        af[mf][kc] = *(const f16x8*)(base + kc * AKC + row * 64 + swz * 16);
    }
  };
  auto readB = [&](f16x8 (&dst)[NH][2], int tt, int nq) {
    const char* base = lds + (tt & 1) * SLOT + ABYT;
#pragma unroll
    for (int nf = 0; nf < NH; nf++) {
      const int row = wn * (BN / WN) + (nq * NH + nf) * 16 + lr;
      const int swz = lg ^ ((row >> 1) & 3);
#pragma unroll
      for (int kc = 0; kc < 2; kc++)
        dst[nf][kc] = *(const f16x8*)(base + kc * BKC + row * 64 + swz * 16);
    }
  };
  auto mmaq = [&](f16x8 (&b)[NH][2], int mq, int nq) {
    __builtin_amdgcn_s_setprio(1);
#pragma unroll
    for (int m = 0; m < MH; m++)
#pragma unroll
      for (int n = 0; n < NH; n++)
#pragma unroll
        for (int kc = 0; kc < 2; kc++)
          acc[mq * MH + m][nq * NH + n] = __builtin_amdgcn_mfma_f32_16x16x32_f16(
              af[m][kc], b[n][kc], acc[mq * MH + m][nq * NH + n], 0, 0, 0);
    __builtin_amdgcn_s_setprio(0);
  };

  const int NT = K >> 6;
  // prologue: stage tiles 0 and 1; gate on tile 0 landed (tile 1 in flight)
  stageA(0, 0); stageA(0, 1); stageB(0, 0); stageB(0, 1);
  stageA(1, 0); stageA(1, 1); stageB(1, 0); stageB(1, 1);
  if constexpr (LPT == 8) asm volatile("s_waitcnt vmcnt(8)" ::: "memory");
  else                    asm volatile("s_waitcnt vmcnt(6)" ::: "memory");
  __builtin_amdgcn_s_barrier();

  for (int tt = 0; tt < NT; ++tt) {
    const bool pf = (tt + 2 < NT);
    // ---- p0: read A.mlo + B.nlo; MFMA q0 ----
    readA(tt, 0);
    readB(bfl, tt, 0);
    __builtin_amdgcn_s_barrier();
    asm volatile("s_waitcnt lgkmcnt(0)" ::: "memory");
    mmaq(bfl, 0, 0);
    __builtin_amdgcn_s_barrier();
    // ---- p1: read B.nhi; MFMA q1 ----
    readB(bfh, tt, 1);
    __builtin_amdgcn_s_barrier();
    asm volatile("s_waitcnt lgkmcnt(0)" ::: "memory");
    mmaq(bfh, 0, 1);
    __builtin_amdgcn_s_barrier();
    // ---- p2: read A.mhi; stage B.kc0(t+2); MFMA q2 ----
    readA(tt, 1);
    asm volatile("" ::: "memory");  // no stage hoist above reads of tile tt
    if (pf) stageB(tt + 2, 0);
    __builtin_amdgcn_s_barrier();
    asm volatile("s_waitcnt lgkmcnt(0)" ::: "memory");
    mmaq(bfl, 1, 0);
    __builtin_amdgcn_s_barrier();
    // ---- p3: stage B.kc1 + A.kc0 + A.kc1 (t+2); vmcnt gate; MFMA q3 ----
    asm volatile("" ::: "memory");
    if (pf) { stageB(tt + 2, 1); stageA(tt + 2, 0); stageA(tt + 2, 1); }
    if (tt < NT - 2) {
      if constexpr (LPT == 8) asm volatile("s_waitcnt vmcnt(8)" ::: "memory");
      else                    asm volatile("s_waitcnt vmcnt(6)" ::: "memory");
    } else if (tt == NT - 2) {
      asm volatile("s_waitcnt vmcnt(0)" ::: "memory");
    }
    __builtin_amdgcn_s_barrier();
    mmaq(bfh, 1, 1);
    __builtin_amdgcn_s_barrier();
  }

#pragma unroll
  for (int n = 0; n < NR; n++) {
    const int col = n0 + wn * (BN / WN) + n * 16 + lr;
    const float sc = (MODE == 0) ? scale_vec[col] : scale_scalar[0];
    const float bs = (MODE == 0) ? bias_vec[col] : 0.f;
#pragma unroll
    for (int m = 0; m < MR; m++)
#pragma unroll
      for (int r2 = 0; r2 < 4; r2++) {
        const int row = m0 + wm * (BM / WM) + m * 16 + lg * 4 + r2;
        const float v = acc[m][n][r2] * sc + bs;
        if constexpr (MODE == 0) {
          f16 h = (f16)v;
          o_hi[(size_t)row * N + col] = h;
          o_lo[(size_t)row * N + col] = (f16)(v - (float)h);
        } else {
          o_f32[(size_t)row * N + col] = v;
        }
      }
  }
}

// ---------------- RoPE on split Q/K (cols 0..5119 of 6144), f32 math ----------------
__global__ __launch_bounds__(256) void k_rope(f16* __restrict__ XH, f16* __restrict__ XL,
                                              const float* __restrict__ cosT,
                                              const float* __restrict__ sinT,
                                              const int* __restrict__ sp) {
  int idx = blockIdx.x * 256 + threadIdx.x;  // 2048 tokens * 40 heads * 64 pairs
  if (idx >= 2048 * 40 * 64) return;
  int p = idx & 63;
  int hh = (idx >> 6) % 40;
  int tkn = idx / (40 * 64);
  int col = (hh < 32) ? hh * 128 + p : 4096 + (hh - 32) * 128 + p;
  size_t i1 = (size_t)tkn * 6144 + col, i2 = i1 + 64;
  float x1 = (float)XH[i1] + (float)XL[i1];
  float x2 = (float)XH[i2] + (float)XL[i2];
  int pos = (tkn & 1023) + sp[0];
  float c = cosT[pos * 128 + p], s = sinT[pos * 128 + p];
  float o1 = x1 * c - x2 * s;
  float o2 = x2 * c + x1 * s;
  f16 h1 = (f16)o1, h2 = (f16)o2;
  XH[i1] = h1; XL[i1] = (f16)(o1 - (float)h1);
  XH[i2] = h2; XL[i2] = (f16)(o2 - (float)h2);
}

// ---------------- flash attention, causal, GQA 4:1 ----------------
__global__ __launch_bounds__(256) void k_attn(const f16* __restrict__ XH,
                                              const f16* __restrict__ XL,
                                              f16* __restrict__ out) {
  __shared__ __align__(16) f16 KsH[32 * 152];
  __shared__ __align__(16) f16 KsL[32 * 152];
  __shared__ __align__(16) f16 VT[128 * 40];
  __shared__ __align__(16) f16 Pb[4 * 16 * 40];
  const int t = threadIdx.x, w = t >> 6, l = t & 63;
  const int lr = l & 15, lg = l >> 4;
  const int qb = blockIdx.x, h = blockIdx.y, b = blockIdx.z;
  const int q0 = qb * 64, kvh = h >> 2;
  const size_t rs_ = 6144;
  const f16* Qh = XH + ((size_t)(b * 1024 + q0)) * rs_ + h * 128;
  const f16* Ql_ = XL + ((size_t)(b * 1024 + q0)) * rs_ + h * 128;
  const f16* KhG = XH + ((size_t)(b * 1024)) * rs_ + 4096 + kvh * 128;
  const f16* KlG = XL + ((size_t)(b * 1024)) * rs_ + 4096 + kvh * 128;
  const f16* VG = XH + ((size_t)(b * 1024)) * rs_ + 5120 + kvh * 128;

  f16x8 qh[4], ql[4];
  {
    size_t qoff = (size_t)(w * 16 + lr) * rs_ + lg * 8;
#pragma unroll
    for (int c = 0; c < 4; c++) {
      qh[c] = *(const f16x8*)(Qh + qoff + c * 32);
      ql[c] = *(const f16x8*)(Ql_ + qoff + c * 32);
    }
  }
  f32x4 accd[8] = {};
  float m_r[4], l_r[4];
#pragma unroll
  for (int r = 0; r < 4; r++) { m_r[r] = -1e30f; l_r[r] = 0.f; }

  const int nkv = q0 + 64;
  for (int kv0 = 0; kv0 < nkv; kv0 += 32) {
    __syncthreads();
#pragma unroll
    for (int i = 0; i < 2; i++) {
      int slot = i * 256 + t, row = slot >> 4, ch = slot & 15;
      size_t go = (size_t)(kv0 + row) * rs_ + ch * 8;
      *(f16x8*)&KsH[row * 152 + ch * 8] = *(const f16x8*)(KhG + go);
      *(f16x8*)&KsL[row * 152 + ch * 8] = *(const f16x8*)(KlG + go);
    }
#pragma unroll
    for (int i = 0; i < 2; i++) {
      int slot = i * 256 + t, row = slot & 31, d8 = slot >> 5;
      f16x8 vv = *(const f16x8*)(VG + (size_t)(kv0 + row) * rs_ + d8 * 8);
#pragma unroll
      for (int j = 0; j < 8; j++) VT[(d8 * 8 + j) * 40 + row] = vv[j];
    }
    __syncthreads();

    f32x4 sc[2] = {};
#pragma unroll
    for (int cb = 0; cb < 2; cb++)
#pragma unroll
      for (int c = 0; c < 4; c++) {
        const f16x8 kh = *(const f16x8*)&KsH[(cb * 16 + lr) * 152 + c * 32 + lg * 8];
        const f16x8 kl = *(const f16x8*)&KsL[(cb * 16 + lr) * 152 + c * 32 + lg * 8];
        sc[cb] = __builtin_amdgcn_mfma_f32_16x16x32_f16(qh[c], kh, sc[cb], 0, 0, 0);
        sc[cb] = __builtin_amdgcn_mfma_f32_16x16x32_f16(qh[c], kl, sc[cb], 0, 0, 0);
        sc[cb] = __builtin_amdgcn_mfma_f32_16x16x32_f16(ql[c], kh, sc[cb], 0, 0, 0);
      }

    const float scale = 0.088388347648318447f;
    float alpha[4], pv[2][4];
#pragma unroll
    for (int r = 0; r < 4; r++) {
      const int qg = q0 + w * 16 + lg * 4 + r;
      float mx = -1e30f;
#pragma unroll
      for (int cb = 0; cb < 2; cb++) {
        const int kg = kv0 + cb * 16 + lr;
        float s = sc[cb][r] * scale;
        s = (kg <= qg) ? s : -1e30f;
        pv[cb][r] = s;
        mx = fmaxf(mx, s);
      }
      mx = fmaxf(mx, __shfl_xor(mx, 1));
      mx = fmaxf(mx, __shfl_xor(mx, 2));
      mx = fmaxf(mx, __shfl_xor(mx, 4));
      mx = fmaxf(mx, __shfl_xor(mx, 8));
      const float mn = fmaxf(m_r[r], mx);
      alpha[r] = __expf(m_r[r] - mn);
      m_r[r] = mn;
      float rsum = 0.f;
#pragma unroll
      for (int cb = 0; cb < 2; cb++) {
        const int kg = kv0 + cb * 16 + lr;
        const float p = (kg <= qg) ? __expf(pv[cb][r] - mn) : 0.f;
        pv[cb][r] = p;
        rsum += p;
      }
      rsum += __shfl_xor(rsum, 1);
      rsum += __shfl_xor(rsum, 2);
      rsum += __shfl_xor(rsum, 4);
      rsum += __shfl_xor(rsum, 8);
      l_r[r] = l_r[r] * alpha[r] + rsum;
    }

    f16* Pw = &Pb[w * 16 * 40];
#pragma unroll
    for (int r = 0; r < 4; r++)
#pragma unroll
      for (int cb = 0; cb < 2; cb++)
        Pw[(lg * 4 + r) * 40 + cb * 16 + lr] = (f16)pv[cb][r];
    const f16x8 pf = *(const f16x8*)&Pw[lr * 40 + lg * 8];

#pragma unroll
    for (int dc = 0; dc < 8; dc++) {
      const f16x8 vf = *(const f16x8*)&VT[(dc * 16 + lr) * 40 + lg * 8];
#pragma unroll
      for (int r = 0; r < 4; r++) accd[dc][r] *= alpha[r];
      accd[dc] = __builtin_amdgcn_mfma_f32_16x16x32_f16(pf, vf, accd[dc], 0, 0, 0);
    }
  }

#pragma unroll
  for (int dc = 0; dc < 8; dc++)
#pragma unroll
    for (int r = 0; r < 4; r++) {
      const int row = b * 1024 + q0 + w * 16 + lg * 4 + r;
      out[(size_t)row * 4096 + h * 128 + dc * 16 + lr] = (f16)(accd[dc][r] / l_r[r]);
    }
}

// ---------------- launch ----------------
extern "C" void kernel_launch(void* const* d_in, const int* in_sizes, int n_in,
                              void* d_out, int out_size, void* d_ws, size_t ws_size,
                              hipStream_t stream) {
  const float* x = (const float*)d_in[0];
  const float* cosT = (const float*)d_in[2];
  const float* sinT = (const float*)d_in[3];
  const int* wq = (const int*)d_in[4];
  const float* bq = (const float*)d_in[5];
  const float* sq = (const float*)d_in[6];
  const int* wk = (const int*)d_in[7];
  const float* bk = (const float*)d_in[8];
  const float* sk = (const float*)d_in[9];
  const int* wv = (const int*)d_in[10];
  const float* bv = (const float*)d_in[11];
  const float* sv = (const float*)d_in[12];
  const int* wo = (const int*)d_in[13];
  const float* so = (const float*)d_in[14];
  const int* sp = (const int*)d_in[15];

  char* ws = (char*)d_ws;
  f16* Acat = (f16*)ws;                        // x hi|lo [2048][8192]; later reused for Wo
  f16* Wcat = (f16*)(ws + 33554432);           // wq|wk|wv f16 [6144][4096]
  f16* XH = (f16*)(ws + 83886080);             // qkv hi [2048][6144]
  f16* XL = (f16*)(ws + 109051904);            // qkv lo
  f16* AO = (f16*)(ws + 134217728);            // attn out [2048][4096]
  float* biasv = (float*)(ws + 150994944);
  float* scalev = (float*)(ws + 151019520);

  hipFuncSetAttribute(reinterpret_cast<const void*>(&k_gemm3<256, 256, 0>),
                      hipFuncAttributeMaxDynamicSharedMemorySize, 131072);
  hipFuncSetAttribute(reinterpret_cast<const void*>(&k_gemm3<128, 256, 1>),
                      hipFuncAttributeMaxDynamicSharedMemorySize, 98304);

  k_cast_x_split<<<8192, 256, 0, stream>>>(x, Acat);
  k_cast_i32_f16<<<16384, 256, 0, stream>>>(wq, Wcat, 16777216);
  k_cast_i32_f16<<<4096, 256, 0, stream>>>(wk, Wcat + (size_t)4096 * 4096, 4194304);
  k_cast_i32_f16<<<4096, 256, 0, stream>>>(wv, Wcat + (size_t)5120 * 4096, 4194304);
  k_prep_bs<<<24, 256, 0, stream>>>(bq, bk, bv, sq, sk, sv, biasv, scalev);

  // fused QKV projection (split-x, K=8192, W k-index wraps at 4096)
  // grid: 8 M-tiles x 24 N-tiles = 192 blocks (M fastest -> W-panel reuse per XCD)
  k_gemm3<256, 256, 0><<<192, 512, 131072, stream>>>(
      Acat, Wcat, XH, XL, nullptr, scalev, biasv, nullptr, 6144, 8192, 4095, 4096, 8);

  k_rope<<<20480, 256, 0, stream>>>(XH, XL, cosT, sinT, sp);

  f16* Wo_ = Acat;  // Acat dead after QKV GEMM
  k_cast_i32_f16<<<16384, 256, 0, stream>>>(wo, Wo_, 16777216);

  k_attn<<<dim3(16, 32, 2), 256, 0, stream>>>(XH, XL, AO);

  // output projection -> f32; 16 M-tiles x 16 N-tiles = 256 blocks (full fill)
  k_gemm3<128, 256, 1><<<256, 512, 98304, stream>>>(
      AO, Wo_, nullptr, nullptr, (float*)d_out, nullptr, nullptr, so, 4096, 4096,
      0x7fffffff, 4096, 16);
}

// Round 4
// 531.806 us; speedup vs baseline: 1.2633x; 1.0363x over previous
//
#include <hip/hip_runtime.h>
#include <hip/hip_bf16.h>
#include <hip/hip_fp16.h>
#include <cstdint>

typedef _Float16 f16;
typedef _Float16 f16x8 __attribute__((ext_vector_type(8)));
typedef _Float16 f16x4 __attribute__((ext_vector_type(4)));
typedef float f32x4 __attribute__((ext_vector_type(4)));

#define DEV_INLINE __device__ __forceinline__

// async 16B/lane global->LDS. LDS dest is wave-uniform base + lane*16.
DEV_INLINE void async_ld16(const void* g, void* l) {
  __builtin_amdgcn_global_load_lds((const __attribute__((address_space(1))) void*)g,
                                   (__attribute__((address_space(3))) void*)l, 16, 0, 0);
}

// ---------------- elementwise prep kernels ----------------

// x f32 [2048][4096] -> Acat f16 [2048][8192] = [hi(4096) | lo(4096)]
__global__ __launch_bounds__(256) void k_cast_x_split(const float* __restrict__ x,
                                                      f16* __restrict__ acat) {
  int idx = blockIdx.x * 256 + threadIdx.x;
  int i = idx * 4;
  if (i >= 2048 * 4096) return;
  float4 v = *(const float4*)&x[i];
  int row = i >> 12, col = i & 4095;
  f16 h0 = (f16)v.x, h1 = (f16)v.y, h2 = (f16)v.z, h3 = (f16)v.w;
  f16x4 hi = {h0, h1, h2, h3};
  f16x4 lo = {(f16)(v.x - (float)h0), (f16)(v.y - (float)h1),
              (f16)(v.z - (float)h2), (f16)(v.w - (float)h3)};
  size_t base = (size_t)row * 8192 + col;
  *(f16x4*)&acat[base] = hi;
  *(f16x4*)&acat[base + 4096] = lo;
}

// int32 weights (values in [-127,127], exact in f16) -> f16
__global__ __launch_bounds__(256) void k_cast_i32_f16(const int* __restrict__ w,
                                                      f16* __restrict__ out, int n) {
  int i = (blockIdx.x * 256 + threadIdx.x) * 4;
  if (i >= n) return;
  int4 v = *(const int4*)&w[i];
  f16x4 o = {(f16)(float)v.x, (f16)(float)v.y, (f16)(float)v.z, (f16)(float)v.w};
  *(f16x4*)&out[i] = o;
}

// concat bias [bq|bk|bv] and per-column scale [sq|sk|sv] over 6144 cols
__global__ __launch_bounds__(256) void k_prep_bs(const float* bq, const float* bk, const float* bv,
                                                 const float* sq, const float* sk, const float* sv,
                                                 float* bias_cat, float* scale_cat) {
  int i = blockIdx.x * 256 + threadIdx.x;
  if (i >= 6144) return;
  float b, s;
  if (i < 4096)      { b = bq[i];        s = sq[0]; }
  else if (i < 5120) { b = bk[i - 4096]; s = sk[0]; }
  else               { b = bv[i - 5120]; s = sv[0]; }
  bias_cat[i] = b;
  scale_cat[i] = s;
}

// ---------------- GEMM v4: 128x128 tile, 4 waves, 2 blocks/CU, 4-phase ring ----------------
// C[M,N] = A[M,K] * W[N,ldw]^T, k wraps by kmask on the W side.
// 256 threads = 4 waves (2M x 2N), wave tile 64x64. Double-buffered LDS (64KB):
//   A as [kc][BM][32 f16], B as [kc][BN][32 f16]; chunk swizzle c^=(row>>1)&3 via
//   global src (linear global_load_lds dest), same XOR on ds_read -> 0 conflicts.
// Per K-tile: 4 phases {ds_read frags | stage part of t+2 -> barrier -> lgkmcnt(0)
//   -> setprio + 8 MFMA -> barrier}; vmcnt(8) once per tile (1 tile in flight).
// 64KB LDS -> 2 blocks/CU co-resident: inter-block overlap fills barrier stalls.
template <int BM, int BN, int MODE>
__global__ __launch_bounds__(256) void k_gemm4(
    const f16* __restrict__ A, const f16* __restrict__ W,
    f16* __restrict__ o_hi, f16* __restrict__ o_lo, float* __restrict__ o_f32,
    const float* __restrict__ scale_vec, const float* __restrict__ bias_vec,
    const float* __restrict__ scale_scalar,
    int N, int K, int kmask, int ldw, int nym) {
  constexpr int TH = 256;
  constexpr int WM = 2, WN = 2;
  constexpr int MR = BM / WM / 16, NR = BN / WN / 16;   // 4, 4
  constexpr int MH = MR / 2, NH = NR / 2;               // 2, 2
  constexpr int AKC = BM * 64;          // bytes per A kc-block (BM rows x 32 f16)
  constexpr int BKC = BN * 64;
  constexpr int ABYT = 2 * AKC, BBYT = 2 * BKC;
  constexpr int SLOT = ABYT + BBYT;     // one K-tile buffer (32KB)
  constexpr int LAH = AKC / (TH * 16);  // loads/thread per A kc-block (2)
  constexpr int LBH = BKC / (TH * 16);
  extern __shared__ __align__(16) char lds[];

  const int t = threadIdx.x, w = t >> 6, ln = t & 63;
  const int lr = ln & 15, lg = ln >> 4;
  const int wn = w & 1, wm = w >> 1;

  // T1: bijective XCD swizzle (m204)
  const int nwg = gridDim.x;
  const int q8 = nwg >> 3, r8 = nwg & 7;
  const int xcd = blockIdx.x & 7, bidx = blockIdx.x >> 3;
  const int sid = (xcd < r8 ? xcd * (q8 + 1) : r8 * (q8 + 1) + (xcd - r8) * q8) + bidx;
  const int m0 = (sid % nym) * BM;
  const int n0 = (sid / nym) * BN;

  // per-thread staging sources (global addr carries the chunk swizzle)
  const f16* aSrc[LAH];
  const f16* bSrc[LBH];
#pragma unroll
  for (int l = 0; l < LAH; l++) {
    int ci = l * TH + t, row = ci >> 2, c = ci & 3;
    int cg = c ^ ((row >> 1) & 3);
    aSrc[l] = A + (size_t)(m0 + row) * K + cg * 8;
  }
#pragma unroll
  for (int l = 0; l < LBH; l++) {
    int ci = l * TH + t, row = ci >> 2, c = ci & 3;
    int cg = c ^ ((row >> 1) & 3);
    bSrc[l] = W + (size_t)(n0 + row) * ldw + cg * 8;
  }

  f32x4 acc[MR][NR] = {};
  f16x8 af[MH][2], bfl[NH][2], bfh[NH][2];

  auto stageA = [&](int tt, int kc) {
    char* dst = lds + (tt & 1) * SLOT + kc * AKC;
    const int ko = tt * 64 + kc * 32;
#pragma unroll
    for (int l = 0; l < LAH; l++)
      async_ld16(aSrc[l] + ko, dst + (l * TH + w * 64) * 16);
  };
  auto stageB = [&](int tt, int kc) {
    char* dst = lds + (tt & 1) * SLOT + ABYT + kc * BKC;
    const int ko = ((tt * 64) & kmask) + kc * 32;
#pragma unroll
    for (int l = 0; l < LBH; l++)
      async_ld16(bSrc[l] + ko, dst + (l * TH + w * 64) * 16);
  };
  auto readA = [&](int tt, int mq) {
    const char* base = lds + (tt & 1) * SLOT;
#pragma unroll
    for (int mf = 0; mf < MH; mf++) {
      const int row = wm * (BM / WM) + (mq * MH + mf) * 16 + lr;
      const int swz = lg ^ ((row >> 1) & 3);
#pragma unroll
      for (int kc = 0; kc < 2; kc++)
        af[mf][kc] = *(const f16x8*)(base + kc * AKC + row * 64 + swz * 16);
    }
  };
  auto readB = [&](f16x8 (&dst)[NH][2], int tt, int nq) {
    const char* base = lds + (tt & 1) * SLOT + ABYT;
#pragma unroll
    for (int nf = 0; nf < NH; nf++) {
      const int row = wn * (BN / WN) + (nq * NH + nf) * 16 + lr;
      const int swz = lg ^ ((row >> 1) & 3);
#pragma unroll
      for (int kc = 0; kc < 2; kc++)
        dst[nf][kc] = *(const f16x8*)(base + kc * BKC + row * 64 + swz * 16);
    }
  };
  auto mmaq = [&](f16x8 (&b)[NH][2], int mq, int nq) {
    __builtin_amdgcn_s_setprio(1);
#pragma unroll
    for (int m = 0; m < MH; m++)
#pragma unroll
      for (int n = 0; n < NH; n++)
#pragma unroll
        for (int kc = 0; kc < 2; kc++)
          acc[mq * MH + m][nq * NH + n] = __builtin_amdgcn_mfma_f32_16x16x32_f16(
              af[m][kc], b[n][kc], acc[mq * MH + m][nq * NH + n], 0, 0, 0);
    __builtin_amdgcn_s_setprio(0);
  };

  const int NT = K >> 6;
  // prologue: stage tiles 0 and 1 (8 loads each); gate on tile 0 landed
  stageA(0, 0); stageA(0, 1); stageB(0, 0); stageB(0, 1);
  stageA(1, 0); stageA(1, 1); stageB(1, 0); stageB(1, 1);
  asm volatile("s_waitcnt vmcnt(8)" ::: "memory");
  __builtin_amdgcn_s_barrier();

  for (int tt = 0; tt < NT; ++tt) {
    const bool pf = (tt + 2 < NT);
    // ---- p0: read A.mlo + B.nlo (8 b128); MFMA q0 ----
    readA(tt, 0);
    readB(bfl, tt, 0);
    __builtin_amdgcn_s_barrier();
    asm volatile("s_waitcnt lgkmcnt(0)" ::: "memory");
    mmaq(bfl, 0, 0);
    __builtin_amdgcn_s_barrier();
    // ---- p1: read B.nhi (4); MFMA q1 ----
    readB(bfh, tt, 1);
    __builtin_amdgcn_s_barrier();
    asm volatile("s_waitcnt lgkmcnt(0)" ::: "memory");
    mmaq(bfh, 0, 1);
    __builtin_amdgcn_s_barrier();
    // ---- p2: read A.mhi (4); stage B.kc0(t+2); MFMA q2 ----
    readA(tt, 1);
    asm volatile("" ::: "memory");  // no stage hoist above reads of tile tt
    if (pf) stageB(tt + 2, 0);
    __builtin_amdgcn_s_barrier();
    asm volatile("s_waitcnt lgkmcnt(0)" ::: "memory");
    mmaq(bfl, 1, 0);
    __builtin_amdgcn_s_barrier();
    // ---- p3: stage B.kc1 + A.kc0 + A.kc1 (t+2); vmcnt gate; MFMA q3 ----
    asm volatile("" ::: "memory");
    if (pf) { stageB(tt + 2, 1); stageA(tt + 2, 0); stageA(tt + 2, 1); }
    if (tt < NT - 2) {
      asm volatile("s_waitcnt vmcnt(8)" ::: "memory");
    } else if (tt == NT - 2) {
      asm volatile("s_waitcnt vmcnt(0)" ::: "memory");
    }
    __builtin_amdgcn_s_barrier();
    mmaq(bfh, 1, 1);
    __builtin_amdgcn_s_barrier();
  }

#pragma unroll
  for (int n = 0; n < NR; n++) {
    const int col = n0 + wn * (BN / WN) + n * 16 + lr;
    const float sc = (MODE == 0) ? scale_vec[col] : scale_scalar[0];
    const float bs = (MODE == 0) ? bias_vec[col] : 0.f;
#pragma unroll
    for (int m = 0; m < MR; m++)
#pragma unroll
      for (int r2 = 0; r2 < 4; r2++) {
        const int row = m0 + wm * (BM / WM) + m * 16 + lg * 4 + r2;
        const float v = acc[m][n][r2] * sc + bs;
        if constexpr (MODE == 0) {
          f16 h = (f16)v;
          o_hi[(size_t)row * N + col] = h;
          o_lo[(size_t)row * N + col] = (f16)(v - (float)h);
        } else {
          o_f32[(size_t)row * N + col] = v;
        }
      }
  }
}

// ---------------- RoPE on split Q/K (cols 0..5119 of 6144), f32 math ----------------
__global__ __launch_bounds__(256) void k_rope(f16* __restrict__ XH, f16* __restrict__ XL,
                                              const float* __restrict__ cosT,
                                              const float* __restrict__ sinT,
                                              const int* __restrict__ sp) {
  int idx = blockIdx.x * 256 + threadIdx.x;  // 2048 tokens * 40 heads * 64 pairs
  if (idx >= 2048 * 40 * 64) return;
  int p = idx & 63;
  int hh = (idx >> 6) % 40;
  int tkn = idx / (40 * 64);
  int col = (hh < 32) ? hh * 128 + p : 4096 + (hh - 32) * 128 + p;
  size_t i1 = (size_t)tkn * 6144 + col, i2 = i1 + 64;
  float x1 = (float)XH[i1] + (float)XL[i1];
  float x2 = (float)XH[i2] + (float)XL[i2];
  int pos = (tkn & 1023) + sp[0];
  float c = cosT[pos * 128 + p], s = sinT[pos * 128 + p];
  float o1 = x1 * c - x2 * s;
  float o2 = x2 * c + x1 * s;
  f16 h1 = (f16)o1, h2 = (f16)o2;
  XH[i1] = h1; XL[i1] = (f16)(o1 - (float)h1);
  XH[i2] = h2; XL[i2] = (f16)(o2 - (float)h2);
}

// ---------------- flash attention, causal, GQA 4:1 ----------------
__global__ __launch_bounds__(256) void k_attn(const f16* __restrict__ XH,
                                              const f16* __restrict__ XL,
                                              f16* __restrict__ out) {
  __shared__ __align__(16) f16 KsH[32 * 152];
  __shared__ __align__(16) f16 KsL[32 * 152];
  __shared__ __align__(16) f16 VT[128 * 40];
  __shared__ __align__(16) f16 Pb[4 * 16 * 40];
  const int t = threadIdx.x, w = t >> 6, l = t & 63;
  const int lr = l & 15, lg = l >> 4;
  const int qb = blockIdx.x, h = blockIdx.y, b = blockIdx.z;
  const int q0 = qb * 64, kvh = h >> 2;
  const size_t rs_ = 6144;
  const f16* Qh = XH + ((size_t)(b * 1024 + q0)) * rs_ + h * 128;
  const f16* Ql_ = XL + ((size_t)(b * 1024 + q0)) * rs_ + h * 128;
  const f16* KhG = XH + ((size_t)(b * 1024)) * rs_ + 4096 + kvh * 128;
  const f16* KlG = XL + ((size_t)(b * 1024)) * rs_ + 4096 + kvh * 128;
  const f16* VG = XH + ((size_t)(b * 1024)) * rs_ + 5120 + kvh * 128;

  f16x8 qh[4], ql[4];
  {
    size_t qoff = (size_t)(w * 16 + lr) * rs_ + lg * 8;
#pragma unroll
    for (int c = 0; c < 4; c++) {
      qh[c] = *(const f16x8*)(Qh + qoff + c * 32);
      ql[c] = *(const f16x8*)(Ql_ + qoff + c * 32);
    }
  }
  f32x4 accd[8] = {};
  float m_r[4], l_r[4];
#pragma unroll
  for (int r = 0; r < 4; r++) { m_r[r] = -1e30f; l_r[r] = 0.f; }

  const int nkv = q0 + 64;
  for (int kv0 = 0; kv0 < nkv; kv0 += 32) {
    __syncthreads();
#pragma unroll
    for (int i = 0; i < 2; i++) {
      int slot = i * 256 + t, row = slot >> 4, ch = slot & 15;
      size_t go = (size_t)(kv0 + row) * rs_ + ch * 8;
      *(f16x8*)&KsH[row * 152 + ch * 8] = *(const f16x8*)(KhG + go);
      *(f16x8*)&KsL[row * 152 + ch * 8] = *(const f16x8*)(KlG + go);
    }
#pragma unroll
    for (int i = 0; i < 2; i++) {
      int slot = i * 256 + t, row = slot & 31, d8 = slot >> 5;
      f16x8 vv = *(const f16x8*)(VG + (size_t)(kv0 + row) * rs_ + d8 * 8);
#pragma unroll
      for (int j = 0; j < 8; j++) VT[(d8 * 8 + j) * 40 + row] = vv[j];
    }
    __syncthreads();

    f32x4 sc[2] = {};
#pragma unroll
    for (int cb = 0; cb < 2; cb++)
#pragma unroll
      for (int c = 0; c < 4; c++) {
        const f16x8 kh = *(const f16x8*)&KsH[(cb * 16 + lr) * 152 + c * 32 + lg * 8];
        const f16x8 kl = *(const f16x8*)&KsL[(cb * 16 + lr) * 152 + c * 32 + lg * 8];
        sc[cb] = __builtin_amdgcn_mfma_f32_16x16x32_f16(qh[c], kh, sc[cb], 0, 0, 0);
        sc[cb] = __builtin_amdgcn_mfma_f32_16x16x32_f16(qh[c], kl, sc[cb], 0, 0, 0);
        sc[cb] = __builtin_amdgcn_mfma_f32_16x16x32_f16(ql[c], kh, sc[cb], 0, 0, 0);
      }

    const float scale = 0.088388347648318447f;
    float alpha[4], pv[2][4];
#pragma unroll
    for (int r = 0; r < 4; r++) {
      const int qg = q0 + w * 16 + lg * 4 + r;
      float mx = -1e30f;
#pragma unroll
      for (int cb = 0; cb < 2; cb++) {
        const int kg = kv0 + cb * 16 + lr;
        float s = sc[cb][r] * scale;
        s = (kg <= qg) ? s : -1e30f;
        pv[cb][r] = s;
        mx = fmaxf(mx, s);
      }
      mx = fmaxf(mx, __shfl_xor(mx, 1));
      mx = fmaxf(mx, __shfl_xor(mx, 2));
      mx = fmaxf(mx, __shfl_xor(mx, 4));
      mx = fmaxf(mx, __shfl_xor(mx, 8));
      const float mn = fmaxf(m_r[r], mx);
      alpha[r] = __expf(m_r[r] - mn);
      m_r[r] = mn;
      float rsum = 0.f;
#pragma unroll
      for (int cb = 0; cb < 2; cb++) {
        const int kg = kv0 + cb * 16 + lr;
        const float p = (kg <= qg) ? __expf(pv[cb][r] - mn) : 0.f;
        pv[cb][r] = p;
        rsum += p;
      }
      rsum += __shfl_xor(rsum, 1);
      rsum += __shfl_xor(rsum, 2);
      rsum += __shfl_xor(rsum, 4);
      rsum += __shfl_xor(rsum, 8);
      l_r[r] = l_r[r] * alpha[r] + rsum;
    }

    f16* Pw = &Pb[w * 16 * 40];
#pragma unroll
    for (int r = 0; r < 4; r++)
#pragma unroll
      for (int cb = 0; cb < 2; cb++)
        Pw[(lg * 4 + r) * 40 + cb * 16 + lr] = (f16)pv[cb][r];
    const f16x8 pf = *(const f16x8*)&Pw[lr * 40 + lg * 8];

#pragma unroll
    for (int dc = 0; dc < 8; dc++) {
      const f16x8 vf = *(const f16x8*)&VT[(dc * 16 + lr) * 40 + lg * 8];
#pragma unroll
      for (int r = 0; r < 4; r++) accd[dc][r] *= alpha[r];
      accd[dc] = __builtin_amdgcn_mfma_f32_16x16x32_f16(pf, vf, accd[dc], 0, 0, 0);
    }
  }

#pragma unroll
  for (int dc = 0; dc < 8; dc++)
#pragma unroll
    for (int r = 0; r < 4; r++) {
      const int row = b * 1024 + q0 + w * 16 + lg * 4 + r;
      out[(size_t)row * 4096 + h * 128 + dc * 16 + lr] = (f16)(accd[dc][r] / l_r[r]);
    }
}

// ---------------- launch ----------------
extern "C" void kernel_launch(void* const* d_in, const int* in_sizes, int n_in,
                              void* d_out, int out_size, void* d_ws, size_t ws_size,
                              hipStream_t stream) {
  const float* x = (const float*)d_in[0];
  const float* cosT = (const float*)d_in[2];
  const float* sinT = (const float*)d_in[3];
  const int* wq = (const int*)d_in[4];
  const float* bq = (const float*)d_in[5];
  const float* sq = (const float*)d_in[6];
  const int* wk = (const int*)d_in[7];
  const float* bk = (const float*)d_in[8];
  const float* sk = (const float*)d_in[9];
  const int* wv = (const int*)d_in[10];
  const float* bv = (const float*)d_in[11];
  const float* sv = (const float*)d_in[12];
  const int* wo = (const int*)d_in[13];
  const float* so = (const float*)d_in[14];
  const int* sp = (const int*)d_in[15];

  char* ws = (char*)d_ws;
  f16* Acat = (f16*)ws;                        // x hi|lo [2048][8192]; later reused for Wo
  f16* Wcat = (f16*)(ws + 33554432);           // wq|wk|wv f16 [6144][4096]
  f16* XH = (f16*)(ws + 83886080);             // qkv hi [2048][6144]
  f16* XL = (f16*)(ws + 109051904);            // qkv lo
  f16* AO = (f16*)(ws + 134217728);            // attn out [2048][4096]
  float* biasv = (float*)(ws + 150994944);
  float* scalev = (float*)(ws + 151019520);

  hipFuncSetAttribute(reinterpret_cast<const void*>(&k_gemm4<128, 128, 0>),
                      hipFuncAttributeMaxDynamicSharedMemorySize, 65536);
  hipFuncSetAttribute(reinterpret_cast<const void*>(&k_gemm4<128, 128, 1>),
                      hipFuncAttributeMaxDynamicSharedMemorySize, 65536);

  k_cast_x_split<<<8192, 256, 0, stream>>>(x, Acat);
  k_cast_i32_f16<<<16384, 256, 0, stream>>>(wq, Wcat, 16777216);
  k_cast_i32_f16<<<4096, 256, 0, stream>>>(wk, Wcat + (size_t)4096 * 4096, 4194304);
  k_cast_i32_f16<<<4096, 256, 0, stream>>>(wv, Wcat + (size_t)5120 * 4096, 4194304);
  k_prep_bs<<<24, 256, 0, stream>>>(bq, bk, bv, sq, sk, sv, biasv, scalev);

  // fused QKV projection (split-x, K=8192, W k-index wraps at 4096)
  // grid: 16 M-tiles x 48 N-tiles = 768 blocks; 2 blocks/CU resident
  k_gemm4<128, 128, 0><<<768, 256, 65536, stream>>>(
      Acat, Wcat, XH, XL, nullptr, scalev, biasv, nullptr, 6144, 8192, 4095, 4096, 16);

  k_rope<<<20480, 256, 0, stream>>>(XH, XL, cosT, sinT, sp);

  f16* Wo_ = Acat;  // Acat dead after QKV GEMM
  k_cast_i32_f16<<<16384, 256, 0, stream>>>(wo, Wo_, 16777216);

  k_attn<<<dim3(16, 32, 2), 256, 0, stream>>>(XH, XL, AO);

  // output projection -> f32; 16 x 32 = 512 blocks = exactly one 2/CU round
  k_gemm4<128, 128, 1><<<512, 256, 65536, stream>>>(
      AO, Wo_, nullptr, nullptr, (float*)d_out, nullptr, nullptr, so, 4096, 4096,
      0x7fffffff, 4096, 16);
}

// Round 6
// 496.947 us; speedup vs baseline: 1.3519x; 1.0701x over previous
//
#include <hip/hip_runtime.h>
#include <hip/hip_bf16.h>
#include <hip/hip_fp16.h>
#include <cstdint>

typedef _Float16 f16;
typedef _Float16 f16x8 __attribute__((ext_vector_type(8)));
typedef _Float16 f16x4 __attribute__((ext_vector_type(4)));
typedef float f32x4 __attribute__((ext_vector_type(4)));

#define DEV_INLINE __device__ __forceinline__

// async 16B/lane global->LDS. LDS dest is wave-uniform base + lane*16.
DEV_INLINE void async_ld16(const void* g, void* l) {
  __builtin_amdgcn_global_load_lds((const __attribute__((address_space(1))) void*)g,
                                   (__attribute__((address_space(3))) void*)l, 16, 0, 0);
}

template <int N>
DEV_INLINE void wait_vm() {
  static_assert(N >= 0 && N <= 12, "gate range");
  if constexpr (N == 0)  asm volatile("s_waitcnt vmcnt(0)" ::: "memory");
  if constexpr (N == 1)  asm volatile("s_waitcnt vmcnt(1)" ::: "memory");
  if constexpr (N == 2)  asm volatile("s_waitcnt vmcnt(2)" ::: "memory");
  if constexpr (N == 3)  asm volatile("s_waitcnt vmcnt(3)" ::: "memory");
  if constexpr (N == 4)  asm volatile("s_waitcnt vmcnt(4)" ::: "memory");
  if constexpr (N == 5)  asm volatile("s_waitcnt vmcnt(5)" ::: "memory");
  if constexpr (N == 6)  asm volatile("s_waitcnt vmcnt(6)" ::: "memory");
  if constexpr (N == 7)  asm volatile("s_waitcnt vmcnt(7)" ::: "memory");
  if constexpr (N == 8)  asm volatile("s_waitcnt vmcnt(8)" ::: "memory");
  if constexpr (N == 9)  asm volatile("s_waitcnt vmcnt(9)" ::: "memory");
  if constexpr (N == 10) asm volatile("s_waitcnt vmcnt(10)" ::: "memory");
  if constexpr (N == 11) asm volatile("s_waitcnt vmcnt(11)" ::: "memory");
  if constexpr (N == 12) asm volatile("s_waitcnt vmcnt(12)" ::: "memory");
}
DEV_INLINE void lgk0() {
  asm volatile("s_waitcnt lgkmcnt(0)" ::: "memory");
  __builtin_amdgcn_sched_barrier(0);
}

// ---------------- elementwise prep kernels ----------------

// x f32 [2048][4096] -> Acat f16 [2048][8192] = [hi(4096) | lo(4096)]
__global__ __launch_bounds__(256) void k_cast_x_split(const float* __restrict__ x,
                                                      f16* __restrict__ acat) {
  int idx = blockIdx.x * 256 + threadIdx.x;
  int i = idx * 4;
  if (i >= 2048 * 4096) return;
  float4 v = *(const float4*)&x[i];
  int row = i >> 12, col = i & 4095;
  f16 h0 = (f16)v.x, h1 = (f16)v.y, h2 = (f16)v.z, h3 = (f16)v.w;
  f16x4 hi = {h0, h1, h2, h3};
  f16x4 lo = {(f16)(v.x - (float)h0), (f16)(v.y - (float)h1),
              (f16)(v.z - (float)h2), (f16)(v.w - (float)h3)};
  size_t base = (size_t)row * 8192 + col;
  *(f16x4*)&acat[base] = hi;
  *(f16x4*)&acat[base + 4096] = lo;
}

// int32 weights (values in [-127,127], exact in f16) -> f16
__global__ __launch_bounds__(256) void k_cast_i32_f16(const int* __restrict__ w,
                                                      f16* __restrict__ out, int n) {
  int i = (blockIdx.x * 256 + threadIdx.x) * 4;
  if (i >= n) return;
  int4 v = *(const int4*)&w[i];
  f16x4 o = {(f16)(float)v.x, (f16)(float)v.y, (f16)(float)v.z, (f16)(float)v.w};
  *(f16x4*)&out[i] = o;
}

// concat bias [bq|bk|bv] and per-column scale [sq|sk|sv] over 6144 cols
__global__ __launch_bounds__(256) void k_prep_bs(const float* bq, const float* bk, const float* bv,
                                                 const float* sq, const float* sk, const float* sv,
                                                 float* bias_cat, float* scale_cat) {
  int i = blockIdx.x * 256 + threadIdx.x;
  if (i >= 6144) return;
  float b, s;
  if (i < 4096)      { b = bq[i];        s = sq[0]; }
  else if (i < 5120) { b = bk[i - 4096]; s = sk[0]; }
  else               { b = bv[i - 5120]; s = sv[0]; }
  bias_cat[i] = b;
  scale_cat[i] = s;
}

// ---------------- GEMM v6: 8-wave exact-fill, 4-phase, gate->barrier->read ----------------
// C[M,N] = A[M,K] * W[N,ldw]^T, k wraps by kmask on the W side.
// 512 threads = 8 waves (2M x 4N), wave tile (BM/2) x (BN/4). BK=64, dbuf LDS.
// CORRECTNESS INVARIANT (fixes round-5 race): every phase's ds_reads are of data
// certified by a vmcnt gate in a PRECEDING phase followed by that phase's
// barriers (gate -> barrier -> read). A wave's vmcnt only covers its own loads;
// the barrier after all waves' gates makes the whole tile visible.
// Issue stream per tile: Ak0, Bk0, Ak1, Bk1 (prologue + p1/p2/p3/p0-next).
// Steady gates: p1 end (certifies Ak1(t),Bk1(t) for p2/p3) and p3 end
// (certifies Ak0(t+1),Bk0(t+1) for next p0); both = vmcnt(2*LB+3). Never 0
// until the final tile. Tail drains: 2LB+2, LB+1, 0.
template <int BM, int BN, int MODE>
__global__ __launch_bounds__(512) void k_gemm6(
    const f16* __restrict__ A, const f16* __restrict__ W,
    f16* __restrict__ o_hi, f16* __restrict__ o_lo, float* __restrict__ o_f32,
    const float* __restrict__ scale_vec, const float* __restrict__ bias_vec,
    const float* __restrict__ scale_scalar,
    int N, int K, int kmask, int ldw, int nym) {
  constexpr int WM = 2, WN = 4;
  constexpr int MR = BM / WM / 16;      // 4
  constexpr int NR = BN / WN / 16;      // 6 (qkv) / 4 (oproj)
  constexpr int NH = NR / 2;            // 3 / 2
  constexpr int AKC = BM * 64;          // bytes per A kc-block
  constexpr int BKC = BN * 64;
  constexpr int SLOT = 2 * (AKC + BKC);
  constexpr int LAH = AKC / 8192;       // loads/thread per A kc-block (1)
  constexpr int LBH = BKC / 8192;       // 3 / 2
  constexpr int GS = 2 * LBH + 3;       // steady gate: 9 / 7
  constexpr int GT1 = 2 * LBH + 2;      // tail gate 1: 8 / 6
  constexpr int GT2 = LBH + 1;          // tail gate 2: 4 / 3
  extern __shared__ __align__(16) char lds[];

  const int t = threadIdx.x, w = t >> 6, ln = t & 63;
  const int lr = ln & 15, lg = ln >> 4;
  const int wn = w & 3, wm = w >> 2;

  // T1: bijective XCD swizzle (m204)
  const int nwg = gridDim.x;
  const int q8 = nwg >> 3, r8 = nwg & 7;
  const int xcd = blockIdx.x & 7, bidx = blockIdx.x >> 3;
  const int sid = (xcd < r8 ? xcd * (q8 + 1) : r8 * (q8 + 1) + (xcd - r8) * q8) + bidx;
  const int m0 = (sid % nym) * BM;
  const int n0 = (sid / nym) * BN;

  // per-thread staging sources (global addr carries the chunk swizzle)
  const f16* aSrc[LAH];
  const f16* bSrc[LBH];
#pragma unroll
  for (int l = 0; l < LAH; l++) {
    int ci = l * 512 + t, row = ci >> 2, c = ci & 3;
    aSrc[l] = A + (size_t)(m0 + row) * K + (c ^ ((row >> 1) & 3)) * 8;
  }
#pragma unroll
  for (int l = 0; l < LBH; l++) {
    int ci = l * 512 + t, row = ci >> 2, c = ci & 3;
    bSrc[l] = W + (size_t)(n0 + row) * ldw + (c ^ ((row >> 1) & 3)) * 8;
  }

  f32x4 acc[MR][NR] = {};
  f16x8 af[MR], bflo[NH], bfhi[NH];

  auto stageA = [&](int tt, int kc) {
    char* dst = lds + (tt & 1) * SLOT + kc * AKC;
    const int ko = tt * 64 + kc * 32;
#pragma unroll
    for (int l = 0; l < LAH; l++)
      async_ld16(aSrc[l] + ko, dst + (l * 512 + w * 64) * 16);
  };
  auto stageB = [&](int tt, int kc) {
    char* dst = lds + (tt & 1) * SLOT + 2 * AKC + kc * BKC;
    const int ko = ((tt * 64) & kmask) + kc * 32;
#pragma unroll
    for (int l = 0; l < LBH; l++)
      async_ld16(bSrc[l] + ko, dst + (l * 512 + w * 64) * 16);
  };
  auto readA = [&](int tt, int kc) {
    const char* base = lds + (tt & 1) * SLOT + kc * AKC;
#pragma unroll
    for (int mf = 0; mf < MR; mf++) {
      const int row = wm * (BM / WM) + mf * 16 + lr;
      af[mf] = *(const f16x8*)(base + row * 64 + (lg ^ ((row >> 1) & 3)) * 16);
    }
  };
  auto readB = [&](f16x8 (&dst)[NH], int tt, int nq, int kc) {
    const char* base = lds + (tt & 1) * SLOT + 2 * AKC + kc * BKC;
#pragma unroll
    for (int nf = 0; nf < NH; nf++) {
      const int row = wn * (BN / WN) + (nq * NH + nf) * 16 + lr;
      dst[nf] = *(const f16x8*)(base + row * 64 + (lg ^ ((row >> 1) & 3)) * 16);
    }
  };
  auto mma = [&](f16x8 (&b)[NH], int nq) {
    __builtin_amdgcn_s_setprio(1);
#pragma unroll
    for (int m = 0; m < MR; m++)
#pragma unroll
      for (int n = 0; n < NH; n++)
        acc[m][nq * NH + n] =
            __builtin_amdgcn_mfma_f32_16x16x32_f16(af[m], b[n], acc[m][nq * NH + n], 0, 0, 0);
    __builtin_amdgcn_s_setprio(0);
  };
  auto bar = [&]() { __builtin_amdgcn_s_barrier(); };

  const int NT = K >> 6;
  // prologue: stage tile0 full + tile1 thru Ak1; gate certifies Ak0(0),Bk0(0);
  // barrier makes it visible block-wide before any read.
  stageA(0, 0); stageB(0, 0); stageA(0, 1); stageB(0, 1);
  stageA(1, 0); stageB(1, 0); stageA(1, 1);
  wait_vm<GS>();
  bar();

  for (int tt = 0; tt + 2 < NT; ++tt) {
    // p0: stage Bk1(t+1); read A.kc0 + B.nlo.kc0 (certified by prev p3 gate+bar)
    stageB(tt + 1, 1);
    readA(tt, 0); readB(bflo, tt, 0, 0);
    bar(); lgk0(); mma(bflo, 0); bar();
    // p1: stage Ak0(t+2); read B.nhi.kc0; GATE (certifies Ak1(t),Bk1(t) for p2/p3)
    stageA(tt + 2, 0);
    readB(bfhi, tt, 1, 0);
    wait_vm<GS>();
    bar(); lgk0(); mma(bfhi, 1); bar();
    // p2: stage Bk0(t+2); read A.kc1 + B.nlo.kc1
    stageB(tt + 2, 0);
    readA(tt, 1); readB(bflo, tt, 0, 1);
    bar(); lgk0(); mma(bflo, 0); bar();
    // p3: stage Ak1(t+2); read B.nhi.kc1; GATE (certifies Ak0(t+1),Bk0(t+1))
    stageA(tt + 2, 1);
    readB(bfhi, tt, 1, 1);
    wait_vm<GS>();
    bar(); lgk0(); mma(bfhi, 1); bar();
  }
  {  // tt = NT-2: stage only Bk1(NT-1); gates shrink (no t+2 stages)
    const int tt = NT - 2;
    stageB(tt + 1, 1);
    readA(tt, 0); readB(bflo, tt, 0, 0);
    bar(); lgk0(); mma(bflo, 0); bar();
    readB(bfhi, tt, 1, 0);
    wait_vm<GT1>();   // certifies Ak1(NT-2), Bk1(NT-2)
    bar(); lgk0(); mma(bfhi, 1); bar();
    readA(tt, 1); readB(bflo, tt, 0, 1);
    bar(); lgk0(); mma(bflo, 0); bar();
    readB(bfhi, tt, 1, 1);
    wait_vm<GT2>();   // certifies Ak0(NT-1), Bk0(NT-1)
    bar(); lgk0(); mma(bfhi, 1); bar();
  }
  {  // tt = NT-1: drain
    const int tt = NT - 1;
    readA(tt, 0); readB(bflo, tt, 0, 0);
    bar(); lgk0(); mma(bflo, 0); bar();
    readB(bfhi, tt, 1, 0);
    wait_vm<0>();     // certifies Ak1(NT-1), Bk1(NT-1)
    bar(); lgk0(); mma(bfhi, 1); bar();
    readA(tt, 1); readB(bflo, tt, 0, 1);
    bar(); lgk0(); mma(bflo, 0); bar();
    readB(bfhi, tt, 1, 1);
    bar(); lgk0(); mma(bfhi, 1);
  }

#pragma unroll
  for (int n = 0; n < NR; n++) {
    const int col = n0 + wn * (BN / WN) + n * 16 + lr;
    const float sc = (MODE == 0) ? scale_vec[col] : scale_scalar[0];
    const float bs = (MODE == 0) ? bias_vec[col] : 0.f;
#pragma unroll
    for (int m = 0; m < MR; m++)
#pragma unroll
      for (int r2 = 0; r2 < 4; r2++) {
        const int row = m0 + wm * (BM / WM) + m * 16 + lg * 4 + r2;
        const float v = acc[m][n][r2] * sc + bs;
        if constexpr (MODE == 0) {
          f16 h = (f16)v;
          o_hi[(size_t)row * N + col] = h;
          o_lo[(size_t)row * N + col] = (f16)(v - (float)h);
        } else {
          o_f32[(size_t)row * N + col] = v;
        }
      }
  }
}

// ---------------- RoPE on split Q/K (cols 0..5119 of 6144), f32 math ----------------
__global__ __launch_bounds__(256) void k_rope(f16* __restrict__ XH, f16* __restrict__ XL,
                                              const float* __restrict__ cosT,
                                              const float* __restrict__ sinT,
                                              const int* __restrict__ sp) {
  int idx = blockIdx.x * 256 + threadIdx.x;  // 2048 tokens * 40 heads * 64 pairs
  if (idx >= 2048 * 40 * 64) return;
  int p = idx & 63;
  int hh = (idx >> 6) % 40;
  int tkn = idx / (40 * 64);
  int col = (hh < 32) ? hh * 128 + p : 4096 + (hh - 32) * 128 + p;
  size_t i1 = (size_t)tkn * 6144 + col, i2 = i1 + 64;
  float x1 = (float)XH[i1] + (float)XL[i1];
  float x2 = (float)XH[i2] + (float)XL[i2];
  int pos = (tkn & 1023) + sp[0];
  float c = cosT[pos * 128 + p], s = sinT[pos * 128 + p];
  float o1 = x1 * c - x2 * s;
  float o2 = x2 * c + x1 * s;
  f16 h1 = (f16)o1, h2 = (f16)o2;
  XH[i1] = h1; XL[i1] = (f16)(o1 - (float)h1);
  XH[i2] = h2; XL[i2] = (f16)(o2 - (float)h2);
}

// ---------------- flash attention, causal, GQA 4:1 ----------------
__global__ __launch_bounds__(256) void k_attn(const f16* __restrict__ XH,
                                              const f16* __restrict__ XL,
                                              f16* __restrict__ out) {
  __shared__ __align__(16) f16 KsH[32 * 152];
  __shared__ __align__(16) f16 KsL[32 * 152];
  __shared__ __align__(16) f16 VT[128 * 40];
  __shared__ __align__(16) f16 Pb[4 * 16 * 40];
  const int t = threadIdx.x, w = t >> 6, l = t & 63;
  const int lr = l & 15, lg = l >> 4;
  const int qb = blockIdx.x, h = blockIdx.y, b = blockIdx.z;
  const int q0 = qb * 64, kvh = h >> 2;
  const size_t rs_ = 6144;
  const f16* Qh = XH + ((size_t)(b * 1024 + q0)) * rs_ + h * 128;
  const f16* Ql_ = XL + ((size_t)(b * 1024 + q0)) * rs_ + h * 128;
  const f16* KhG = XH + ((size_t)(b * 1024)) * rs_ + 4096 + kvh * 128;
  const f16* KlG = XL + ((size_t)(b * 1024)) * rs_ + 4096 + kvh * 128;
  const f16* VG = XH + ((size_t)(b * 1024)) * rs_ + 5120 + kvh * 128;

  f16x8 qh[4], ql[4];
  {
    size_t qoff = (size_t)(w * 16 + lr) * rs_ + lg * 8;
#pragma unroll
    for (int c = 0; c < 4; c++) {
      qh[c] = *(const f16x8*)(Qh + qoff + c * 32);
      ql[c] = *(const f16x8*)(Ql_ + qoff + c * 32);
    }
  }
  f32x4 accd[8] = {};
  float m_r[4], l_r[4];
#pragma unroll
  for (int r = 0; r < 4; r++) { m_r[r] = -1e30f; l_r[r] = 0.f; }

  const int nkv = q0 + 64;
  for (int kv0 = 0; kv0 < nkv; kv0 += 32) {
    __syncthreads();
#pragma unroll
    for (int i = 0; i < 2; i++) {
      int slot = i * 256 + t, row = slot >> 4, ch = slot & 15;
      size_t go = (size_t)(kv0 + row) * rs_ + ch * 8;
      *(f16x8*)&KsH[row * 152 + ch * 8] = *(const f16x8*)(KhG + go);
      *(f16x8*)&KsL[row * 152 + ch * 8] = *(const f16x8*)(KlG + go);
    }
#pragma unroll
    for (int i = 0; i < 2; i++) {
      int slot = i * 256 + t, row = slot & 31, d8 = slot >> 5;
      f16x8 vv = *(const f16x8*)(VG + (size_t)(kv0 + row) * rs_ + d8 * 8);
#pragma unroll
      for (int j = 0; j < 8; j++) VT[(d8 * 8 + j) * 40 + row] = vv[j];
    }
    __syncthreads();

    f32x4 sc[2] = {};
#pragma unroll
    for (int cb = 0; cb < 2; cb++)
#pragma unroll
      for (int c = 0; c < 4; c++) {
        const f16x8 kh = *(const f16x8*)&KsH[(cb * 16 + lr) * 152 + c * 32 + lg * 8];
        const f16x8 kl = *(const f16x8*)&KsL[(cb * 16 + lr) * 152 + c * 32 + lg * 8];
        sc[cb] = __builtin_amdgcn_mfma_f32_16x16x32_f16(qh[c], kh, sc[cb], 0, 0, 0);
        sc[cb] = __builtin_amdgcn_mfma_f32_16x16x32_f16(qh[c], kl, sc[cb], 0, 0, 0);
        sc[cb] = __builtin_amdgcn_mfma_f32_16x16x32_f16(ql[c], kh, sc[cb], 0, 0, 0);
      }

    const float scale = 0.088388347648318447f;
    float alpha[4], pv[2][4];
#pragma unroll
    for (int r = 0; r < 4; r++) {
      const int qg = q0 + w * 16 + lg * 4 + r;
      float mx = -1e30f;
#pragma unroll
      for (int cb = 0; cb < 2; cb++) {
        const int kg = kv0 + cb * 16 + lr;
        float s = sc[cb][r] * scale;
        s = (kg <= qg) ? s : -1e30f;
        pv[cb][r] = s;
        mx = fmaxf(mx, s);
      }
      mx = fmaxf(mx, __shfl_xor(mx, 1));
      mx = fmaxf(mx, __shfl_xor(mx, 2));
      mx = fmaxf(mx, __shfl_xor(mx, 4));
      mx = fmaxf(mx, __shfl_xor(mx, 8));
      const float mn = fmaxf(m_r[r], mx);
      alpha[r] = __expf(m_r[r] - mn);
      m_r[r] = mn;
      float rsum = 0.f;
#pragma unroll
      for (int cb = 0; cb < 2; cb++) {
        const int kg = kv0 + cb * 16 + lr;
        const float p = (kg <= qg) ? __expf(pv[cb][r] - mn) : 0.f;
        pv[cb][r] = p;
        rsum += p;
      }
      rsum += __shfl_xor(rsum, 1);
      rsum += __shfl_xor(rsum, 2);
      rsum += __shfl_xor(rsum, 4);
      rsum += __shfl_xor(rsum, 8);
      l_r[r] = l_r[r] * alpha[r] + rsum;
    }

    f16* Pw = &Pb[w * 16 * 40];
#pragma unroll
    for (int r = 0; r < 4; r++)
#pragma unroll
      for (int cb = 0; cb < 2; cb++)
        Pw[(lg * 4 + r) * 40 + cb * 16 + lr] = (f16)pv[cb][r];
    const f16x8 pf = *(const f16x8*)&Pw[lr * 40 + lg * 8];

#pragma unroll
    for (int dc = 0; dc < 8; dc++) {
      const f16x8 vf = *(const f16x8*)&VT[(dc * 16 + lr) * 40 + lg * 8];
#pragma unroll
      for (int r = 0; r < 4; r++) accd[dc][r] *= alpha[r];
      accd[dc] = __builtin_amdgcn_mfma_f32_16x16x32_f16(pf, vf, accd[dc], 0, 0, 0);
    }
  }

#pragma unroll
  for (int dc = 0; dc < 8; dc++)
#pragma unroll
    for (int r = 0; r < 4; r++) {
      const int row = b * 1024 + q0 + w * 16 + lg * 4 + r;
      out[(size_t)row * 4096 + h * 128 + dc * 16 + lr] = (f16)(accd[dc][r] / l_r[r]);
    }
}

// ---------------- launch ----------------
extern "C" void kernel_launch(void* const* d_in, const int* in_sizes, int n_in,
                              void* d_out, int out_size, void* d_ws, size_t ws_size,
                              hipStream_t stream) {
  const float* x = (const float*)d_in[0];
  const float* cosT = (const float*)d_in[2];
  const float* sinT = (const float*)d_in[3];
  const int* wq = (const int*)d_in[4];
  const float* bq = (const float*)d_in[5];
  const float* sq = (const float*)d_in[6];
  const int* wk = (const int*)d_in[7];
  const float* bk = (const float*)d_in[8];
  const float* sk = (const float*)d_in[9];
  const int* wv = (const int*)d_in[10];
  const float* bv = (const float*)d_in[11];
  const float* sv = (const float*)d_in[12];
  const int* wo = (const int*)d_in[13];
  const float* so = (const float*)d_in[14];
  const int* sp = (const int*)d_in[15];

  char* ws = (char*)d_ws;
  f16* Acat = (f16*)ws;                        // x hi|lo [2048][8192]; later reused for Wo
  f16* Wcat = (f16*)(ws + 33554432);           // wq|wk|wv f16 [6144][4096]
  f16* XH = (f16*)(ws + 83886080);             // qkv hi [2048][6144]
  f16* XL = (f16*)(ws + 109051904);            // qkv lo
  f16* AO = (f16*)(ws + 134217728);            // attn out [2048][4096]
  float* biasv = (float*)(ws + 150994944);
  float* scalev = (float*)(ws + 151019520);

  hipFuncSetAttribute(reinterpret_cast<const void*>(&k_gemm6<128, 384, 0>),
                      hipFuncAttributeMaxDynamicSharedMemorySize, 131072);
  hipFuncSetAttribute(reinterpret_cast<const void*>(&k_gemm6<128, 256, 1>),
                      hipFuncAttributeMaxDynamicSharedMemorySize, 98304);

  k_cast_x_split<<<8192, 256, 0, stream>>>(x, Acat);
  k_cast_i32_f16<<<16384, 256, 0, stream>>>(wq, Wcat, 16777216);
  k_cast_i32_f16<<<4096, 256, 0, stream>>>(wk, Wcat + (size_t)4096 * 4096, 4194304);
  k_cast_i32_f16<<<4096, 256, 0, stream>>>(wv, Wcat + (size_t)5120 * 4096, 4194304);
  k_prep_bs<<<24, 256, 0, stream>>>(bq, bk, bv, sq, sk, sv, biasv, scalev);

  // fused QKV projection (split-x, K=8192, W k-index wraps at 4096)
  // grid: 16 M-tiles x 16 N-tiles(384) = 256 blocks = exactly 1/CU
  k_gemm6<128, 384, 0><<<256, 512, 131072, stream>>>(
      Acat, Wcat, XH, XL, nullptr, scalev, biasv, nullptr, 6144, 8192, 4095, 4096, 16);

  k_rope<<<20480, 256, 0, stream>>>(XH, XL, cosT, sinT, sp);

  f16* Wo_ = Acat;  // Acat dead after QKV GEMM
  k_cast_i32_f16<<<16384, 256, 0, stream>>>(wo, Wo_, 16777216);

  k_attn<<<dim3(16, 32, 2), 256, 0, stream>>>(XH, XL, AO);

  // output projection -> f32; 16 x 16 = 256 blocks = exactly 1/CU
  k_gemm6<128, 256, 1><<<256, 512, 98304, stream>>>(
      AO, Wo_, nullptr, nullptr, (float*)d_out, nullptr, nullptr, so, 4096, 4096,
      0x7fffffff, 4096, 16);
}